// Round 1
// baseline (1150.115 us; speedup 1.0000x reference)
//
#include <hip/hip_runtime.h>

#define EPSF 1e-8f

typedef __attribute__((ext_vector_type(8))) __bf16 bf16x8;
typedef __attribute__((ext_vector_type(4))) float f32x4;

constexpr int S = 256;
constexpr int NB = 128;
constexpr int D2 = 512;
constexpr int HALF = 256;
constexpr size_t NORM_ELEMS = (size_t)2 * 33 * NB * S;  // per tensor (p or q)

// norm slot layout per (dir): slots 0..7  -> W[dir]   (m_full weights W0/W1)
//                             slots 8..15 -> W[2+dir] (maxpool weights W2/W3)
//                             slots 16..23-> W[4], slots 24..31 -> W[5], slot 32 -> unweighted
__device__ __forceinline__ size_t normIdx(int dir, int slot, int b, int row) {
    return (((size_t)dir * 33 + slot) * NB + b) * S + row;
}

// ---------------------------------------------------------------------------
// K0: all weighted norms.  grid = 2(tensor) * 2(dir) * 128(b), block = 256 (one row each)
// ---------------------------------------------------------------------------
__global__ __launch_bounds__(256) void k_norms(const float* __restrict__ p,
                                               const float* __restrict__ q,
                                               const float* __restrict__ W,
                                               float* __restrict__ ws)
{
    int blk = blockIdx.x;
    int b = blk & 127;
    int dir = (blk >> 7) & 1;
    int tensor = blk >> 8;
    const float* x = tensor ? q : p;
    float* outN = ws + (size_t)tensor * NORM_ELEMS;

    __shared__ float W2[32][HALF];  // squared weight rows for slots 0..31
    for (int e = threadIdx.x; e < 32 * HALF; e += 256) {
        int slot = e >> 8;
        int d = e & (HALF - 1);
        int wl = slot >> 3, l = slot & 7;
        int wi = (wl == 0) ? dir : (wl == 1) ? (2 + dir) : (wl == 2) ? 4 : 5;
        float w = W[(size_t)(wi * 8 + l) * HALF + d];
        W2[slot][d] = w * w;
    }
    __syncthreads();

    int row = threadIdx.x;
    const float* xr = x + ((size_t)row * NB + b) * D2 + dir * HALF;
    float acc[33];
#pragma unroll
    for (int i = 0; i < 33; i++) acc[i] = 0.f;
    for (int d4 = 0; d4 < HALF; d4 += 4) {
        float4 v = *(const float4*)(xr + d4);
        float xx = v.x * v.x, yy = v.y * v.y, zz = v.z * v.z, ww = v.w * v.w;
        acc[32] += xx + yy + zz + ww;
#pragma unroll
        for (int slot = 0; slot < 32; slot++) {
            acc[slot] += xx * W2[slot][d4] + yy * W2[slot][d4 + 1]
                       + zz * W2[slot][d4 + 2] + ww * W2[slot][d4 + 3];
        }
    }
#pragma unroll
    for (int slot = 0; slot < 33; slot++)
        outN[normIdx(dir, slot, b, row)] = sqrtf(acc[slot]);
}

// ---------------------------------------------------------------------------
// K1: m_full (out segments 0..15).  grid = 2(dir)*256(s)*4(bgrp), block 256 = 32 b x 8 l
// ---------------------------------------------------------------------------
__global__ __launch_bounds__(256) void k_full(const float* __restrict__ p,
                                              const float* __restrict__ q,
                                              const float* __restrict__ W,
                                              const float* __restrict__ ws,
                                              float* __restrict__ out)
{
    int blk = blockIdx.x;
    int bg = blk & 3;
    int s = (blk >> 2) & 255;
    int dir = blk >> 10;
    int tid = threadIdx.x;
    int b = bg * 32 + (tid >> 3);
    int l = tid & 7;
    int wi = dir;  // W0 for fw, W1 for bw

    __shared__ float W2[8][HALF];
    for (int e = tid; e < 8 * HALF; e += 256) {
        int ll = e >> 8, d = e & (HALF - 1);
        float w = W[(size_t)(wi * 8 + ll) * HALF + d];
        W2[ll][d] = w * w;
    }
    __syncthreads();

    int qrow = dir ? 0 : (S - 1);
    const float* pr = p + ((size_t)s * NB + b) * D2 + dir * HALF;
    const float* qr = q + ((size_t)qrow * NB + b) * D2 + dir * HALF;
    float num = 0.f;
    for (int d4 = 0; d4 < HALF; d4 += 4) {
        float4 pv = *(const float4*)(pr + d4);
        float4 qv = *(const float4*)(qr + d4);
        num += pv.x * qv.x * W2[l][d4] + pv.y * qv.y * W2[l][d4 + 1]
             + pv.z * qv.z * W2[l][d4 + 2] + pv.w * qv.w * W2[l][d4 + 3];
    }
    const float* normP = ws;
    const float* normQ = ws + NORM_ELEMS;
    float n1 = normP[normIdx(dir, l, b, s)];
    float n2 = normQ[normIdx(dir, l, b, qrow)];
    out[((size_t)s * NB + b) * 64 + dir * 8 + l] = num / fmaxf(n1 * n2, EPSF);
}

// ---------------------------------------------------------------------------
// K2: maxpool match via bf16 MFMA (out segments 16..31).
// block per (dir,b,l,s_chunk64): C[64 s][256 t] = (p*W^2) . q^T, K=256, then max over t.
// grid = 8192, blockIdx = grp + 256*sub (same (dir,b) => same XCD under %8 round robin)
// ---------------------------------------------------------------------------
__global__ __launch_bounds__(256) void k_maxpool(const float* __restrict__ p,
                                                 const float* __restrict__ q,
                                                 const float* __restrict__ W,
                                                 const float* __restrict__ ws,
                                                 float* __restrict__ out)
{
    int grp = blockIdx.x & 255;
    int sub = blockIdx.x >> 8;
    int b = grp & 127, dir = grp >> 7;
    int l = sub >> 2, sc = sub & 3;
    int s0 = sc * 64;
    int wi = 2 + dir;
    int tid = threadIdx.x;

    __shared__ __align__(16) __bf16 Al[64][72];
    __shared__ __align__(16) __bf16 Bl[256][72];
    __shared__ float W2[HALF];
    __shared__ float n1l[64];
    __shared__ float n2l[S];
    __shared__ float wmax[4][64];

    const float* normP = ws;
    const float* normQ = ws + NORM_ELEMS;
    int slot = 8 + l;
    for (int e = tid; e < HALF; e += 256) {
        float w = W[(size_t)(wi * 8 + l) * HALF + e];
        W2[e] = w * w;
        n2l[e] = normQ[normIdx(dir, slot, b, e)];
    }
    if (tid < 64) n1l[tid] = normP[normIdx(dir, slot, b, s0 + tid)];
    __syncthreads();

    int wave = tid >> 6, lane = tid & 63;
    int colq = lane & 15, quad = lane >> 4;
    int r = tid >> 4, c4 = tid & 15;

    f32x4 acc[4][4];
#pragma unroll
    for (int mi = 0; mi < 4; mi++)
#pragma unroll
        for (int ni = 0; ni < 4; ni++)
#pragma unroll
            for (int k = 0; k < 4; k++) acc[mi][ni][k] = 0.f;

    const float* pbase = p + (size_t)b * D2 + dir * HALF;
    const float* qbase = q + (size_t)b * D2 + dir * HALF;

    for (int k0 = 0; k0 < HALF; k0 += 64) {
        __syncthreads();
        // stage A = bf16(p * W^2): 64 x 64
#pragma unroll
        for (int pass = 0; pass < 4; pass++) {
            int row = pass * 16 + r;
            int col = c4 * 4;
            float4 v = *(const float4*)(pbase + (size_t)(s0 + row) * NB * D2 + k0 + col);
            Al[row][col + 0] = (__bf16)(v.x * W2[k0 + col + 0]);
            Al[row][col + 1] = (__bf16)(v.y * W2[k0 + col + 1]);
            Al[row][col + 2] = (__bf16)(v.z * W2[k0 + col + 2]);
            Al[row][col + 3] = (__bf16)(v.w * W2[k0 + col + 3]);
        }
        // stage B = bf16(q): 256 x 64
#pragma unroll
        for (int pass = 0; pass < 16; pass++) {
            int row = pass * 16 + r;
            int col = c4 * 4;
            float4 v = *(const float4*)(qbase + (size_t)row * NB * D2 + k0 + col);
            Bl[row][col + 0] = (__bf16)v.x;
            Bl[row][col + 1] = (__bf16)v.y;
            Bl[row][col + 2] = (__bf16)v.z;
            Bl[row][col + 3] = (__bf16)v.w;
        }
        __syncthreads();
#pragma unroll
        for (int ks = 0; ks < 2; ks++) {
            int kk = ks * 32 + quad * 8;
            bf16x8 af[4], bfr[4];
#pragma unroll
            for (int mi = 0; mi < 4; mi++)
                af[mi] = *(const bf16x8*)&Al[mi * 16 + colq][kk];
#pragma unroll
            for (int ni = 0; ni < 4; ni++)
                bfr[ni] = *(const bf16x8*)&Bl[wave * 64 + ni * 16 + colq][kk];
#pragma unroll
            for (int mi = 0; mi < 4; mi++)
#pragma unroll
                for (int ni = 0; ni < 4; ni++)
                    acc[mi][ni] = __builtin_amdgcn_mfma_f32_16x16x32_bf16(
                        af[mi], bfr[ni], acc[mi][ni], 0, 0, 0);
        }
    }

    // epilogue: sim = C / max(n1*n2, eps), max over t within block (block covers all t)
#pragma unroll
    for (int mi = 0; mi < 4; mi++) {
#pragma unroll
        for (int rg = 0; rg < 4; rg++) {
            int sl = mi * 16 + quad * 4 + rg;
            float n1v = n1l[sl];
            float m = -3.4e38f;
#pragma unroll
            for (int ni = 0; ni < 4; ni++) {
                int t = wave * 64 + ni * 16 + colq;
                float sim = acc[mi][ni][rg] / fmaxf(n1v * n2l[t], EPSF);
                m = fmaxf(m, sim);
            }
#pragma unroll
            for (int msk = 1; msk < 16; msk <<= 1)
                m = fmaxf(m, __shfl_xor(m, msk, 64));
            if (colq == 0) wmax[wave][sl] = m;
        }
    }
    __syncthreads();
    if (tid < 64) {
        float m = fmaxf(fmaxf(wmax[0][tid], wmax[1][tid]),
                        fmaxf(wmax[2][tid], wmax[3][tid]));
        out[((size_t)(s0 + tid) * NB + b) * 64 + 16 + dir * 8 + l] = m;
    }
}

// ---------------------------------------------------------------------------
// K3: attentive match, fp32 (out segments 32..63).
// block per (dir,b,s_tile16); t processed in chunks of 32; h kept in registers.
// grid = 4096, blockIdx = st*256 + dir*128 + b (same (dir,b) => same XCD)
// ---------------------------------------------------------------------------
__global__ __launch_bounds__(256) void k_attentive(const float* __restrict__ p,
                                                   const float* __restrict__ q,
                                                   const float* __restrict__ W,
                                                   const float* __restrict__ ws,
                                                   float* __restrict__ out)
{
    int blk = blockIdx.x;
    int b = blk & 127;
    int dir = (blk >> 7) & 1;
    int st = blk >> 8;
    int tid = threadIdx.x;
    const float* normP = ws;
    const float* normQ = ws + NORM_ELEMS;

    __shared__ __align__(16) float pt[16][260];
    __shared__ __align__(16) float qt[32][260];
    __shared__ float al[16][33];
    __shared__ float asum[16], amax[16];
    __shared__ int aidx[16];
    __shared__ float np0[16];
    __shared__ float nq0[S];

    int s0 = st * 16;
    const float* pbase = p + (size_t)b * D2 + dir * HALF;
    const float* qbase = q + (size_t)b * D2 + dir * HALF;

    for (int e = tid; e < 16 * 64; e += 256) {
        int rr = e >> 6, d4 = (e & 63) * 4;
        *(float4*)&pt[rr][d4] = *(const float4*)(pbase + (size_t)(s0 + rr) * NB * D2 + d4);
    }
    nq0[tid] = normQ[normIdx(dir, 32, b, tid)];
    if (tid < 16) {
        np0[tid] = normP[normIdx(dir, 32, b, s0 + tid)];
        asum[tid] = 0.f;
        amax[tid] = -3.4e38f;
        aidx[tid] = 0;
    }

    float4 hh0 = {0.f, 0.f, 0.f, 0.f}, hh1 = {0.f, 0.f, 0.f, 0.f};
    float4 hh2 = {0.f, 0.f, 0.f, 0.f}, hh3 = {0.f, 0.f, 0.f, 0.f};

    for (int tc = 0; tc < 8; tc++) {
        __syncthreads();
        for (int e = tid; e < 32 * 64; e += 256) {
            int rr = e >> 6, d4 = (e & 63) * 4;
            *(float4*)&qt[rr][d4] =
                *(const float4*)(qbase + (size_t)(tc * 32 + rr) * NB * D2 + d4);
        }
        __syncthreads();
        {
            int sl = tid >> 4, tlp = tid & 15;
            float a0 = 0.f, a1 = 0.f;
            for (int d4 = 0; d4 < HALF; d4 += 4) {
                float4 pv = *(const float4*)&pt[sl][d4];
                float4 q0 = *(const float4*)&qt[tlp][d4];
                float4 q1 = *(const float4*)&qt[tlp + 16][d4];
                a0 += pv.x * q0.x + pv.y * q0.y + pv.z * q0.z + pv.w * q0.w;
                a1 += pv.x * q1.x + pv.y * q1.y + pv.z * q1.z + pv.w * q1.w;
            }
            int t0 = tc * 32 + tlp;
            al[sl][tlp] = a0 / fmaxf(np0[sl] * nq0[t0], EPSF);
            al[sl][tlp + 16] = a1 / fmaxf(np0[sl] * nq0[t0 + 16], EPSF);
        }
        __syncthreads();
        if (tid < 16) {
            float sm = asum[tid], mx = amax[tid];
            int mi = aidx[tid];
#pragma unroll
            for (int tl = 0; tl < 32; tl++) {
                float a = al[tid][tl];
                sm += a;
                if (a > mx) { mx = a; mi = tc * 32 + tl; }  // strict > keeps first index
            }
            asum[tid] = sm; amax[tid] = mx; aidx[tid] = mi;
        }
        {
            int sl = tid & 15, dg = tid >> 4;
#pragma unroll
            for (int tl = 0; tl < 32; tl++) {
                float a = al[sl][tl];
                float4 q0 = *(const float4*)&qt[tl][dg * 16 + 0];
                float4 q1 = *(const float4*)&qt[tl][dg * 16 + 4];
                float4 q2 = *(const float4*)&qt[tl][dg * 16 + 8];
                float4 q3 = *(const float4*)&qt[tl][dg * 16 + 12];
                hh0.x += a * q0.x; hh0.y += a * q0.y; hh0.z += a * q0.z; hh0.w += a * q0.w;
                hh1.x += a * q1.x; hh1.y += a * q1.y; hh1.z += a * q1.z; hh1.w += a * q1.w;
                hh2.x += a * q2.x; hh2.y += a * q2.y; hh2.z += a * q2.z; hh2.w += a * q2.w;
                hh3.x += a * q3.x; hh3.y += a * q3.y; hh3.z += a * q3.z; hh3.w += a * q3.w;
            }
        }
    }
    __syncthreads();
    // write normalized h_mean into qt rows 0..15
    {
        int sl = tid & 15, dg = tid >> 4;
        float sdiv = asum[sl];
        qt[sl][dg * 16 + 0] = hh0.x / sdiv;  qt[sl][dg * 16 + 1] = hh0.y / sdiv;
        qt[sl][dg * 16 + 2] = hh0.z / sdiv;  qt[sl][dg * 16 + 3] = hh0.w / sdiv;
        qt[sl][dg * 16 + 4] = hh1.x / sdiv;  qt[sl][dg * 16 + 5] = hh1.y / sdiv;
        qt[sl][dg * 16 + 6] = hh1.z / sdiv;  qt[sl][dg * 16 + 7] = hh1.w / sdiv;
        qt[sl][dg * 16 + 8] = hh2.x / sdiv;  qt[sl][dg * 16 + 9] = hh2.y / sdiv;
        qt[sl][dg * 16 + 10] = hh2.z / sdiv; qt[sl][dg * 16 + 11] = hh2.w / sdiv;
        qt[sl][dg * 16 + 12] = hh3.x / sdiv; qt[sl][dg * 16 + 13] = hh3.y / sdiv;
        qt[sl][dg * 16 + 14] = hh3.z / sdiv; qt[sl][dg * 16 + 15] = hh3.w / sdiv;
    }
    __syncthreads();

    if (tid < 128) {
        int s = tid >> 3, l = tid & 7;
        int gidx = aidx[s];
        const float* qm = qbase + (size_t)gidx * NB * D2;
        const float* w4r = W + (size_t)(4 * 8 + l) * HALF;
        const float* w5r = W + (size_t)(5 * 8 + l) * HALF;
        float num4 = 0.f, nh4 = 0.f, num5 = 0.f;
        for (int d4 = 0; d4 < HALF; d4 += 4) {
            float4 w4 = *(const float4*)(w4r + d4);
            float4 w5 = *(const float4*)(w5r + d4);
            float4 qv = *(const float4*)(qm + d4);
            float4 pv = *(const float4*)&pt[s][d4];
            float4 hv = *(const float4*)&qt[s][d4];
            float a0 = w4.x * w4.x, a1 = w4.y * w4.y, a2 = w4.z * w4.z, a3 = w4.w * w4.w;
            float b0 = w5.x * w5.x, b1 = w5.y * w5.y, b2 = w5.z * w5.z, b3 = w5.w * w5.w;
            num4 += pv.x * a0 * hv.x + pv.y * a1 * hv.y + pv.z * a2 * hv.z + pv.w * a3 * hv.w;
            nh4 += hv.x * hv.x * a0 + hv.y * hv.y * a1 + hv.z * hv.z * a2 + hv.w * hv.w * a3;
            num5 += pv.x * b0 * qv.x + pv.y * b1 * qv.y + pv.z * b2 * qv.z + pv.w * b3 * qv.w;
        }
        float np4v = normP[normIdx(dir, 16 + l, b, s0 + s)];
        float np5v = normP[normIdx(dir, 24 + l, b, s0 + s)];
        float nq5v = normQ[normIdx(dir, 24 + l, b, gidx)];
        float matt = num4 / fmaxf(np4v * sqrtf(nh4), EPSF);
        float mmax = num5 / fmaxf(np5v * nq5v, EPSF);
        size_t ob = ((size_t)(s0 + s) * NB + b) * 64;
        out[ob + 32 + dir * 8 + l] = matt;
        out[ob + 48 + dir * 8 + l] = mmax;
    }
}

// ---------------------------------------------------------------------------
extern "C" void kernel_launch(void* const* d_in, const int* in_sizes, int n_in,
                              void* d_out, int out_size, void* d_ws, size_t ws_size,
                              hipStream_t stream)
{
    (void)in_sizes; (void)n_in; (void)out_size; (void)ws_size;
    const float* p = (const float*)d_in[0];
    const float* q = (const float*)d_in[1];
    const float* W = (const float*)d_in[2];
    float* out = (float*)d_out;
    float* ws = (float*)d_ws;

    hipLaunchKernelGGL(k_norms, dim3(512), dim3(256), 0, stream, p, q, W, ws);
    hipLaunchKernelGGL(k_full, dim3(2048), dim3(256), 0, stream, p, q, W, ws, out);
    hipLaunchKernelGGL(k_maxpool, dim3(8192), dim3(256), 0, stream, p, q, W, ws, out);
    hipLaunchKernelGGL(k_attentive, dim3(4096), dim3(256), 0, stream, p, q, W, ws, out);
}

// Round 2
// 1065.751 us; speedup vs baseline: 1.0792x; 1.0792x over previous
//
#include <hip/hip_runtime.h>
#include <hip/hip_bf16.h>

#define EPSF 1e-8f

typedef __attribute__((ext_vector_type(8))) __bf16 bf16x8;
typedef __attribute__((ext_vector_type(4))) float f32x4;

constexpr int S = 256;
constexpr int NB = 128;
constexpr int D2 = 512;
constexpr int HALF = 256;
constexpr int NBD2 = NB * D2;
constexpr size_t NORM_ELEMS = (size_t)2 * 33 * NB * S;  // per tensor (p or q)

// norm slot layout per (dir): slots 0..7  -> W[dir]   (m_full weights W0/W1)
//                             slots 8..15 -> W[2+dir] (maxpool weights W2/W3)
//                             slots 16..23-> W[4], slots 24..31 -> W[5], slot 32 -> unweighted
__device__ __forceinline__ size_t normIdx(int dir, int slot, int b, int row) {
    return (((size_t)dir * 33 + slot) * NB + b) * S + row;
}

__device__ __forceinline__ uint pack2bf(float a, float b) {
    __hip_bfloat162 t = __float22bfloat162_rn(make_float2(a, b));
    uint u;
    __builtin_memcpy(&u, &t, 4);
    return u;
}

// ---------------------------------------------------------------------------
// K0: all weighted norms.  grid = 2(tensor) * 2(dir) * 128(b), block = 256
// ---------------------------------------------------------------------------
__global__ __launch_bounds__(256) void k_norms(const float* __restrict__ p,
                                               const float* __restrict__ q,
                                               const float* __restrict__ W,
                                               float* __restrict__ ws)
{
    int blk = blockIdx.x;
    int b = blk & 127;
    int dir = (blk >> 7) & 1;
    int tensor = blk >> 8;
    const float* x = tensor ? q : p;
    float* outN = ws + (size_t)tensor * NORM_ELEMS;

    __shared__ float W2[32][HALF];
    for (int e = threadIdx.x; e < 32 * HALF; e += 256) {
        int slot = e >> 8;
        int d = e & (HALF - 1);
        int wl = slot >> 3, l = slot & 7;
        int wi = (wl == 0) ? dir : (wl == 1) ? (2 + dir) : (wl == 2) ? 4 : 5;
        float w = W[(size_t)(wi * 8 + l) * HALF + d];
        W2[slot][d] = w * w;
    }
    __syncthreads();

    int row = threadIdx.x;
    const float* xr = x + ((size_t)row * NB + b) * D2 + dir * HALF;
    float acc[33];
#pragma unroll
    for (int i = 0; i < 33; i++) acc[i] = 0.f;
    for (int d4 = 0; d4 < HALF; d4 += 4) {
        float4 v = *(const float4*)(xr + d4);
        float xx = v.x * v.x, yy = v.y * v.y, zz = v.z * v.z, ww = v.w * v.w;
        acc[32] += xx + yy + zz + ww;
#pragma unroll
        for (int slot = 0; slot < 32; slot++) {
            acc[slot] += xx * W2[slot][d4] + yy * W2[slot][d4 + 1]
                       + zz * W2[slot][d4 + 2] + ww * W2[slot][d4 + 3];
        }
    }
#pragma unroll
    for (int slot = 0; slot < 33; slot++)
        outN[normIdx(dir, slot, b, row)] = sqrtf(acc[slot]);
}

// ---------------------------------------------------------------------------
// K1: m_full (out segments 0..15).  grid = 2(dir)*256(s)*4(bgrp), block 256
// ---------------------------------------------------------------------------
__global__ __launch_bounds__(256) void k_full(const float* __restrict__ p,
                                              const float* __restrict__ q,
                                              const float* __restrict__ W,
                                              const float* __restrict__ ws,
                                              float* __restrict__ out)
{
    int blk = blockIdx.x;
    int bg = blk & 3;
    int s = (blk >> 2) & 255;
    int dir = blk >> 10;
    int tid = threadIdx.x;
    int b = bg * 32 + (tid >> 3);
    int l = tid & 7;
    int wi = dir;

    __shared__ float W2[8][HALF];
    for (int e = tid; e < 8 * HALF; e += 256) {
        int ll = e >> 8, d = e & (HALF - 1);
        float w = W[(size_t)(wi * 8 + ll) * HALF + d];
        W2[ll][d] = w * w;
    }
    __syncthreads();

    int qrow = dir ? 0 : (S - 1);
    const float* pr = p + ((size_t)s * NB + b) * D2 + dir * HALF;
    const float* qr = q + ((size_t)qrow * NB + b) * D2 + dir * HALF;
    float num = 0.f;
    for (int d4 = 0; d4 < HALF; d4 += 4) {
        float4 pv = *(const float4*)(pr + d4);
        float4 qv = *(const float4*)(qr + d4);
        num += pv.x * qv.x * W2[l][d4] + pv.y * qv.y * W2[l][d4 + 1]
             + pv.z * qv.z * W2[l][d4 + 2] + pv.w * qv.w * W2[l][d4 + 3];
    }
    const float* normP = ws;
    const float* normQ = ws + NORM_ELEMS;
    float n1 = normP[normIdx(dir, l, b, s)];
    float n2 = normQ[normIdx(dir, l, b, qrow)];
    out[((size_t)s * NB + b) * 64 + dir * 8 + l] = num / fmaxf(n1 * n2, EPSF);
}

// ---------------------------------------------------------------------------
// K2: maxpool match via bf16 MFMA, 2 l per block (out segments 16..31).
// grid = 4096: grp = blk&255 -> (dir,b); sub = blk>>8: lp = sub>>2 (l-pair), sc = sub&3
// ---------------------------------------------------------------------------
__global__ __launch_bounds__(256) void k_maxpool2(const float* __restrict__ p,
                                                  const float* __restrict__ q,
                                                  const float* __restrict__ W,
                                                  const float* __restrict__ ws,
                                                  float* __restrict__ out)
{
    int grp = blockIdx.x & 255;
    int sub = blockIdx.x >> 8;
    int b = grp & 127, dir = grp >> 7;
    int lp = sub >> 2, sc = sub & 3;
    int l0 = lp * 2;
    int s0 = sc * 64;
    int wi = 2 + dir;
    int tid = threadIdx.x;

    __shared__ __align__(16) __bf16 Al[2][64][72];
    __shared__ __align__(16) __bf16 Bl[256][72];
    __shared__ __align__(16) float W2[2][HALF];
    __shared__ float n1l[2][64];
    __shared__ float n2l[2][HALF];
    __shared__ float wmax[2][4][64];

    const float* normP = ws;
    const float* normQ = ws + NORM_ELEMS;
    {
        int e = tid;  // HALF == 256 == blockDim
#pragma unroll
        for (int ll = 0; ll < 2; ll++) {
            float w = W[(size_t)(wi * 8 + l0 + ll) * HALF + e];
            W2[ll][e] = w * w;
            n2l[ll][e] = normQ[normIdx(dir, 8 + l0 + ll, b, e)];
        }
    }
    if (tid < 64) {
#pragma unroll
        for (int ll = 0; ll < 2; ll++)
            n1l[ll][tid] = normP[normIdx(dir, 8 + l0 + ll, b, s0 + tid)];
    }
    __syncthreads();

    int wave = tid >> 6, lane = tid & 63;
    int colq = lane & 15, quad = lane >> 4;
    int r = tid >> 4, c4 = tid & 15;

    f32x4 acc[2][4][4];
#pragma unroll
    for (int ll = 0; ll < 2; ll++)
#pragma unroll
        for (int mi = 0; mi < 4; mi++)
#pragma unroll
            for (int ni = 0; ni < 4; ni++)
#pragma unroll
                for (int k = 0; k < 4; k++) acc[ll][mi][ni][k] = 0.f;

    const float* pbase = p + (size_t)b * D2 + dir * HALF;
    const float* qbase = q + (size_t)b * D2 + dir * HALF;

    for (int k0 = 0; k0 < HALF; k0 += 64) {
        __syncthreads();
        // stage A for both l: 64 x 64 each
#pragma unroll
        for (int pass = 0; pass < 4; pass++) {
            int row = pass * 16 + r;
            int col = c4 * 4;
            float4 v = *(const float4*)(pbase + (size_t)(s0 + row) * NBD2 + k0 + col);
#pragma unroll
            for (int ll = 0; ll < 2; ll++) {
                float4 wv = *(const float4*)&W2[ll][k0 + col];
                uint* dst = (uint*)&Al[ll][row][col];
                dst[0] = pack2bf(v.x * wv.x, v.y * wv.y);
                dst[1] = pack2bf(v.z * wv.z, v.w * wv.w);
            }
        }
        // stage B = bf16(q): 256 x 64 (shared by both l)
#pragma unroll
        for (int pass = 0; pass < 16; pass++) {
            int row = pass * 16 + r;
            int col = c4 * 4;
            float4 v = *(const float4*)(qbase + (size_t)row * NBD2 + k0 + col);
            uint* dst = (uint*)&Bl[row][col];
            dst[0] = pack2bf(v.x, v.y);
            dst[1] = pack2bf(v.z, v.w);
        }
        __syncthreads();
#pragma unroll
        for (int ks = 0; ks < 2; ks++) {
            int kk = ks * 32 + quad * 8;
            bf16x8 bfr[4];
#pragma unroll
            for (int ni = 0; ni < 4; ni++)
                bfr[ni] = *(const bf16x8*)&Bl[wave * 64 + ni * 16 + colq][kk];
#pragma unroll
            for (int ll = 0; ll < 2; ll++) {
                bf16x8 afl[4];
#pragma unroll
                for (int mi = 0; mi < 4; mi++)
                    afl[mi] = *(const bf16x8*)&Al[ll][mi * 16 + colq][kk];
#pragma unroll
                for (int mi = 0; mi < 4; mi++)
#pragma unroll
                    for (int ni = 0; ni < 4; ni++)
                        acc[ll][mi][ni] = __builtin_amdgcn_mfma_f32_16x16x32_bf16(
                            afl[mi], bfr[ni], acc[ll][mi][ni], 0, 0, 0);
            }
        }
    }

    // epilogue per l
#pragma unroll
    for (int ll = 0; ll < 2; ll++) {
#pragma unroll
        for (int mi = 0; mi < 4; mi++) {
#pragma unroll
            for (int rg = 0; rg < 4; rg++) {
                int sl = mi * 16 + quad * 4 + rg;
                float n1v = n1l[ll][sl];
                float m = -3.4e38f;
#pragma unroll
                for (int ni = 0; ni < 4; ni++) {
                    int t = wave * 64 + ni * 16 + colq;
                    float sim = acc[ll][mi][ni][rg] / fmaxf(n1v * n2l[ll][t], EPSF);
                    m = fmaxf(m, sim);
                }
#pragma unroll
                for (int msk = 1; msk < 16; msk <<= 1)
                    m = fmaxf(m, __shfl_xor(m, msk, 64));
                if (colq == 0) wmax[ll][wave][sl] = m;
            }
        }
    }
    __syncthreads();
    if (tid < 128) {
        int ll = tid >> 6, sl = tid & 63;
        float m = fmaxf(fmaxf(wmax[ll][0][sl], wmax[ll][1][sl]),
                        fmaxf(wmax[ll][2][sl], wmax[ll][3][sl]));
        out[((size_t)(s0 + sl) * NB + b) * 64 + 16 + dir * 8 + l0 + ll] = m;
    }
}

// ---------------------------------------------------------------------------
// K3: attentive match via MFMA (out segments 32..63).
// Block = (dir, b, s-chunk64). grid = 1024: blk = (dir*128+b) + 256*st.
// Phase1: alpha = p.q^T, split-bf16 (3 MFMAs) -> fp32-grade accuracy.
// Phase2: normalize, sum/argmax reductions, alpha -> bf16 LDS (A layout).
// Phase3: h = alpha . q  (bf16 MFMA, q transposed-staged per chunk).
// Phase4: epilogue GEMMs E1=p.h, E2=h.h, E3=p.qmax against [W4²;W5²] (bf16).
// ---------------------------------------------------------------------------
__global__ __launch_bounds__(256) void k_attentive2(const float* __restrict__ p,
                                                    const float* __restrict__ q,
                                                    const float* __restrict__ W,
                                                    const float* __restrict__ ws,
                                                    float* __restrict__ out)
{
    int blk = blockIdx.x;
    int grp = blk & 255;
    int st = blk >> 8;
    int b = grp & 127, dir = grp >> 7;
    int s0 = st * 64;
    int tid = threadIdx.x;
    int wave = tid >> 6, lane = tid & 63;
    int colq = lane & 15, quad = lane >> 4;

    const float* normP = ws;
    const float* normQ = ws + NORM_ELEMS;

    // region0 union: P1 staging (51200 B) | P2/P3 alphaB+qTl (54272 B) | P4 E+W45 (36096 B)
    __shared__ __align__(16) char region0[54272];
    __bf16* Qhi = (__bf16*)region0;              // [256][40]
    __bf16* Qlo = Qhi + 256 * 40;                // [256][40]
    __bf16* Phi = Qhi + 2 * 256 * 40;            // [64][40]
    __bf16* Plo = Phi + 64 * 40;                 // [64][40]
    __bf16* alphaB = (__bf16*)region0;           // [64][264]
    __bf16* qTl = alphaB + 64 * 264;             // [256][40]
    __bf16* E1 = (__bf16*)region0;               // [64][72]
    __bf16* E2 = E1 + 64 * 72;
    __bf16* E3 = E2 + 64 * 72;
    __bf16* W45 = E3 + 64 * 72;                  // [16][264]

    __shared__ __align__(16) float np0s[64];
    __shared__ __align__(16) float nq0s[256];
    __shared__ float redS[4][64];
    __shared__ float redM[4][64];
    __shared__ int   redI[4][64];
    __shared__ float asumS[64];
    __shared__ int   aidxS[64];

    if (tid < 64) np0s[tid] = normP[normIdx(dir, 32, b, s0 + tid)];
    nq0s[tid] = normQ[normIdx(dir, 32, b, tid)];

    const float* pbase = p + (size_t)b * D2 + dir * HALF;
    const float* qbase = q + (size_t)b * D2 + dir * HALF;

    f32x4 acc[4][4];
#pragma unroll
    for (int mi = 0; mi < 4; mi++)
#pragma unroll
        for (int ni = 0; ni < 4; ni++)
#pragma unroll
            for (int k = 0; k < 4; k++) acc[mi][ni][k] = 0.f;

    // ---------------- Phase 1: alpha num via split-bf16 MFMA, K chunks of 32
    for (int kc = 0; kc < 8; kc++) {
        int k0 = kc * 32;
        __syncthreads();
        // stage q: 256 rows x 32 cols (8 passes of 32 rows)
        {
            int rr = tid >> 3, cc = (tid & 7) * 4;
#pragma unroll
            for (int pass = 0; pass < 8; pass++) {
                int row = pass * 32 + rr;
                float4 v = *(const float4*)(qbase + (size_t)row * NBD2 + k0 + cc);
                uint ux = __float_as_uint(v.x), uy = __float_as_uint(v.y);
                uint uz = __float_as_uint(v.z), uw = __float_as_uint(v.w);
                uint* dh = (uint*)&Qhi[row * 40 + cc];
                dh[0] = (ux >> 16) | (uy & 0xffff0000u);
                dh[1] = (uz >> 16) | (uw & 0xffff0000u);
                float lx = v.x - __uint_as_float(ux & 0xffff0000u);
                float ly = v.y - __uint_as_float(uy & 0xffff0000u);
                float lz = v.z - __uint_as_float(uz & 0xffff0000u);
                float lw = v.w - __uint_as_float(uw & 0xffff0000u);
                uint* dl = (uint*)&Qlo[row * 40 + cc];
                dl[0] = pack2bf(lx, ly);
                dl[1] = pack2bf(lz, lw);
            }
        }
        // stage p: 64 rows x 32 cols
        {
            int row = tid >> 2, cc = (tid & 3) * 8;
#pragma unroll
            for (int h = 0; h < 2; h++) {
                int c = cc + h * 4;
                float4 v = *(const float4*)(pbase + (size_t)(s0 + row) * NBD2 + k0 + c);
                uint ux = __float_as_uint(v.x), uy = __float_as_uint(v.y);
                uint uz = __float_as_uint(v.z), uw = __float_as_uint(v.w);
                uint* dh = (uint*)&Phi[row * 40 + c];
                dh[0] = (ux >> 16) | (uy & 0xffff0000u);
                dh[1] = (uz >> 16) | (uw & 0xffff0000u);
                float lx = v.x - __uint_as_float(ux & 0xffff0000u);
                float ly = v.y - __uint_as_float(uy & 0xffff0000u);
                float lz = v.z - __uint_as_float(uz & 0xffff0000u);
                float lw = v.w - __uint_as_float(uw & 0xffff0000u);
                uint* dl = (uint*)&Plo[row * 40 + c];
                dl[0] = pack2bf(lx, ly);
                dl[1] = pack2bf(lz, lw);
            }
        }
        __syncthreads();
        {
            int kk = quad * 8;
            bf16x8 ah[4], al_[4], bh[4], bl_[4];
#pragma unroll
            for (int mi = 0; mi < 4; mi++) {
                ah[mi] = *(const bf16x8*)&Phi[(mi * 16 + colq) * 40 + kk];
                al_[mi] = *(const bf16x8*)&Plo[(mi * 16 + colq) * 40 + kk];
            }
#pragma unroll
            for (int ni = 0; ni < 4; ni++) {
                bh[ni] = *(const bf16x8*)&Qhi[(wave * 64 + ni * 16 + colq) * 40 + kk];
                bl_[ni] = *(const bf16x8*)&Qlo[(wave * 64 + ni * 16 + colq) * 40 + kk];
            }
#pragma unroll
            for (int mi = 0; mi < 4; mi++)
#pragma unroll
                for (int ni = 0; ni < 4; ni++) {
                    acc[mi][ni] = __builtin_amdgcn_mfma_f32_16x16x32_bf16(
                        ah[mi], bh[ni], acc[mi][ni], 0, 0, 0);
                    acc[mi][ni] = __builtin_amdgcn_mfma_f32_16x16x32_bf16(
                        ah[mi], bl_[ni], acc[mi][ni], 0, 0, 0);
                    acc[mi][ni] = __builtin_amdgcn_mfma_f32_16x16x32_bf16(
                        al_[mi], bh[ni], acc[mi][ni], 0, 0, 0);
                }
        }
    }

    // ---------------- Phase 2: normalize, alpha->bf16 LDS, sum/argmax
    __syncthreads();
#pragma unroll
    for (int mi = 0; mi < 4; mi++) {
        int rowbase = mi * 16 + quad * 4;
        float4 npv = *(const float4*)&np0s[rowbase];
        float npa[4] = {npv.x, npv.y, npv.z, npv.w};
        float av[4][4];
#pragma unroll
        for (int ni = 0; ni < 4; ni++) {
            float nqv = nq0s[wave * 64 + ni * 16 + colq];
#pragma unroll
            for (int rg = 0; rg < 4; rg++)
                av[ni][rg] = acc[mi][ni][rg] / fmaxf(npa[rg] * nqv, EPSF);
        }
#pragma unroll
        for (int ni = 0; ni < 4; ni++)
#pragma unroll
            for (int rg = 0; rg < 4; rg++)
                alphaB[(rowbase + rg) * 264 + wave * 64 + ni * 16 + colq] =
                    (__bf16)av[ni][rg];
#pragma unroll
        for (int rg = 0; rg < 4; rg++) {
            float sm = av[0][rg] + av[1][rg] + av[2][rg] + av[3][rg];
            float mx = av[0][rg];
            int ix = wave * 64 + colq;
#pragma unroll
            for (int ni = 1; ni < 4; ni++) {
                if (av[ni][rg] > mx) { mx = av[ni][rg]; ix = wave * 64 + ni * 16 + colq; }
            }
#pragma unroll
            for (int off = 1; off < 16; off <<= 1) {
                sm += __shfl_xor(sm, off, 64);
                float m2 = __shfl_xor(mx, off, 64);
                int i2 = __shfl_xor(ix, off, 64);
                if (m2 > mx || (m2 == mx && i2 < ix)) { mx = m2; ix = i2; }
            }
            if (colq == 0) {
                redS[wave][rowbase + rg] = sm;
                redM[wave][rowbase + rg] = mx;
                redI[wave][rowbase + rg] = ix;
            }
        }
    }
    __syncthreads();
    if (tid < 64) {
        float sm = redS[0][tid] + redS[1][tid] + redS[2][tid] + redS[3][tid];
        float mx = redM[0][tid];
        int ix = redI[0][tid];
#pragma unroll
        for (int w = 1; w < 4; w++) {
            float m2 = redM[w][tid];
            int i2 = redI[w][tid];
            if (m2 > mx || (m2 == mx && i2 < ix)) { mx = m2; ix = i2; }
        }
        asumS[tid] = sm;
        aidxS[tid] = ix;
    }

    // ---------------- Phase 3: h = alpha . q  (bf16), K = t chunks of 32
#pragma unroll
    for (int mi = 0; mi < 4; mi++)
#pragma unroll
        for (int ni = 0; ni < 4; ni++)
#pragma unroll
            for (int k = 0; k < 4; k++) acc[mi][ni][k] = 0.f;

    for (int tc = 0; tc < 8; tc++) {
        __syncthreads();
        // stage qT chunk: 32 t x 256 d -> qTl[d][t]
        {
            int tq = tid & 31, dg = tid >> 5;
#pragma unroll
            for (int i = 0; i < 8; i++) {
                int d = dg * 32 + i * 4;
                float4 v = *(const float4*)(qbase + (size_t)(tc * 32 + tq) * NBD2 + d);
                qTl[(d + 0) * 40 + tq] = (__bf16)v.x;
                qTl[(d + 1) * 40 + tq] = (__bf16)v.y;
                qTl[(d + 2) * 40 + tq] = (__bf16)v.z;
                qTl[(d + 3) * 40 + tq] = (__bf16)v.w;
            }
        }
        __syncthreads();
        {
            int kk = quad * 8;
            bf16x8 af[4], bf_[4];
#pragma unroll
            for (int mi = 0; mi < 4; mi++)
                af[mi] = *(const bf16x8*)&alphaB[(mi * 16 + colq) * 264 + tc * 32 + kk];
#pragma unroll
            for (int ni = 0; ni < 4; ni++)
                bf_[ni] = *(const bf16x8*)&qTl[(wave * 64 + ni * 16 + colq) * 40 + kk];
#pragma unroll
            for (int mi = 0; mi < 4; mi++)
#pragma unroll
                for (int ni = 0; ni < 4; ni++)
                    acc[mi][ni] = __builtin_amdgcn_mfma_f32_16x16x32_bf16(
                        af[mi], bf_[ni], acc[mi][ni], 0, 0, 0);
        }
    }

    // ---------------- Phase 4: epilogue GEMMs
    __syncthreads();
    // stage W45 = bf16([W4^2 ; W5^2]): 16 rows x 256 d
    {
        int n = tid >> 4, i = tid & 15;
        int wrow = (n < 8) ? (4 * 8 + n) : (5 * 8 + (n - 8));
#pragma unroll
        for (int j = 0; j < 16; j++) {
            int d = i * 16 + j;
            float w = W[(size_t)wrow * HALF + d];
            W45[n * 264 + d] = (__bf16)(w * w);
        }
    }

    f32x4 c1, c2, c3;
#pragma unroll
    for (int k = 0; k < 4; k++) { c1[k] = 0.f; c2[k] = 0.f; c3[k] = 0.f; }

    for (int kd = 0; kd < 4; kd++) {
        __syncthreads();
        if (wave == kd) {
            // this wave's acc covers d in [kd*64, kd*64+64): build E chunks
#pragma unroll
            for (int mi = 0; mi < 4; mi++) {
#pragma unroll
                for (int rg = 0; rg < 4; rg++) {
                    int sl = mi * 16 + quad * 4 + rg;
                    int gidx = aidxS[sl];
                    const float* prow = pbase + (size_t)(s0 + sl) * NBD2;
                    const float* qrow = qbase + (size_t)gidx * NBD2;
#pragma unroll
                    for (int ni = 0; ni < 4; ni++) {
                        int d = kd * 64 + ni * 16 + colq;
                        float pv = prow[d];
                        float qv = qrow[d];
                        float hv = acc[mi][ni][rg];
                        int ec = ni * 16 + colq;
                        E1[sl * 72 + ec] = (__bf16)(pv * hv);
                        E2[sl * 72 + ec] = (__bf16)(hv * hv);
                        E3[sl * 72 + ec] = (__bf16)(pv * qv);
                    }
                }
            }
        }
        __syncthreads();
#pragma unroll
        for (int ks = 0; ks < 2; ks++) {
            int kk = ks * 32 + quad * 8;
            bf16x8 ea = *(const bf16x8*)&E1[(wave * 16 + colq) * 72 + kk];
            bf16x8 eb = *(const bf16x8*)&E2[(wave * 16 + colq) * 72 + kk];
            bf16x8 ec = *(const bf16x8*)&E3[(wave * 16 + colq) * 72 + kk];
            bf16x8 wb = *(const bf16x8*)&W45[colq * 264 + kd * 64 + kk];
            c1 = __builtin_amdgcn_mfma_f32_16x16x32_bf16(ea, wb, c1, 0, 0, 0);
            c2 = __builtin_amdgcn_mfma_f32_16x16x32_bf16(eb, wb, c2, 0, 0, 0);
            c3 = __builtin_amdgcn_mfma_f32_16x16x32_bf16(ec, wb, c3, 0, 0, 0);
        }
    }

    // final writes: rows s = wave*16 + quad*4 + rg, col = colq
#pragma unroll
    for (int rg = 0; rg < 4; rg++) {
        int sl = wave * 16 + quad * 4 + rg;
        size_t ob = ((size_t)(s0 + sl) * NB + b) * 64;
        if (colq < 8) {
            int l = colq;
            float np4 = normP[normIdx(dir, 16 + l, b, s0 + sl)];
            float nh = sqrtf(fmaxf(c2[rg], 0.f));
            float sgn = (asumS[sl] < 0.f) ? -1.f : 1.f;
            out[ob + 32 + dir * 8 + l] = sgn * c1[rg] / fmaxf(np4 * nh, EPSF);
        } else {
            int l = colq - 8;
            float np5 = normP[normIdx(dir, 24 + l, b, s0 + sl)];
            float nq5 = normQ[normIdx(dir, 24 + l, b, aidxS[sl])];
            out[ob + 48 + dir * 8 + l] = c3[rg] / fmaxf(np5 * nq5, EPSF);
        }
    }
}

// ---------------------------------------------------------------------------
extern "C" void kernel_launch(void* const* d_in, const int* in_sizes, int n_in,
                              void* d_out, int out_size, void* d_ws, size_t ws_size,
                              hipStream_t stream)
{
    (void)in_sizes; (void)n_in; (void)out_size; (void)ws_size;
    const float* p = (const float*)d_in[0];
    const float* q = (const float*)d_in[1];
    const float* W = (const float*)d_in[2];
    float* out = (float*)d_out;
    float* ws = (float*)d_ws;

    hipLaunchKernelGGL(k_norms, dim3(512), dim3(256), 0, stream, p, q, W, ws);
    hipLaunchKernelGGL(k_full, dim3(2048), dim3(256), 0, stream, p, q, W, ws, out);
    hipLaunchKernelGGL(k_maxpool2, dim3(4096), dim3(256), 0, stream, p, q, W, ws, out);
    hipLaunchKernelGGL(k_attentive2, dim3(1024), dim3(256), 0, stream, p, q, W, ws, out);
}

// Round 3
// 870.010 us; speedup vs baseline: 1.3220x; 1.2250x over previous
//
#include <hip/hip_runtime.h>
#include <hip/hip_bf16.h>

#define EPSF 1e-8f

typedef __attribute__((ext_vector_type(8))) __bf16 bf16x8;
typedef __attribute__((ext_vector_type(4))) float f32x4;

constexpr int S = 256;
constexpr int NB = 128;
constexpr int D2 = 512;
constexpr int HALF = 256;
constexpr int NBD2 = NB * D2;
constexpr size_t NORM_ELEMS = (size_t)2 * 33 * NB * S;  // per tensor (p or q)

// ws byte offsets
constexpr size_t OFF_ASUM  = 17301504;   // f32 [2*128*256]
constexpr size_t OFF_AIDX  = 17563648;   // i32 [2*128*256]
constexpr size_t OFF_QHI   = 17825792;   // bf16 [2*128][256 t][256 d]
constexpr size_t OFF_QLO   = 51380224;   // bf16 same
constexpr size_t OFF_QT    = 84934656;   // bf16 [2*128][256 d][256 t]
constexpr size_t OFF_ALPHA = 118489088;  // bf16 [2*128][256 s][256 t]
constexpr size_t WS_NEED   = 152043520;

__device__ __forceinline__ size_t normIdx(int dir, int slot, int b, int row) {
    return (((size_t)dir * 33 + slot) * NB + b) * S + row;
}

__device__ __forceinline__ uint pack2bf(float a, float b) {
    __hip_bfloat162 t = __float22bfloat162_rn(make_float2(a, b));
    uint u;
    __builtin_memcpy(&u, &t, 4);
    return u;
}

__device__ __forceinline__ bf16x8 ld8(const __bf16* p8) {  // 8-byte-aligned load
    union { uint2 u[2]; bf16x8 v; } t;
    t.u[0] = *(const uint2*)p8;
    t.u[1] = *(const uint2*)(p8 + 4);
    return t.v;
}

// ---------------------------------------------------------------------------
// K0: all weighted norms (unchanged, passing).
// ---------------------------------------------------------------------------
__global__ __launch_bounds__(256) void k_norms(const float* __restrict__ p,
                                               const float* __restrict__ q,
                                               const float* __restrict__ W,
                                               float* __restrict__ ws)
{
    int blk = blockIdx.x;
    int b = blk & 127;
    int dir = (blk >> 7) & 1;
    int tensor = blk >> 8;
    const float* x = tensor ? q : p;
    float* outN = ws + (size_t)tensor * NORM_ELEMS;

    __shared__ float W2[32][HALF];
    for (int e = threadIdx.x; e < 32 * HALF; e += 256) {
        int slot = e >> 8;
        int d = e & (HALF - 1);
        int wl = slot >> 3, l = slot & 7;
        int wi = (wl == 0) ? dir : (wl == 1) ? (2 + dir) : (wl == 2) ? 4 : 5;
        float w = W[(size_t)(wi * 8 + l) * HALF + d];
        W2[slot][d] = w * w;
    }
    __syncthreads();

    int row = threadIdx.x;
    const float* xr = x + ((size_t)row * NB + b) * D2 + dir * HALF;
    float acc[33];
#pragma unroll
    for (int i = 0; i < 33; i++) acc[i] = 0.f;
    for (int d4 = 0; d4 < HALF; d4 += 4) {
        float4 v = *(const float4*)(xr + d4);
        float xx = v.x * v.x, yy = v.y * v.y, zz = v.z * v.z, ww = v.w * v.w;
        acc[32] += xx + yy + zz + ww;
#pragma unroll
        for (int slot = 0; slot < 32; slot++) {
            acc[slot] += xx * W2[slot][d4] + yy * W2[slot][d4 + 1]
                       + zz * W2[slot][d4 + 2] + ww * W2[slot][d4 + 3];
        }
    }
#pragma unroll
    for (int slot = 0; slot < 33; slot++)
        outN[normIdx(dir, slot, b, row)] = sqrtf(acc[slot]);
}

// ---------------------------------------------------------------------------
// K_packA: Qhi = rne_bf16(q), Qlo = rne_bf16(q - Qhi). grid 1024.
// ---------------------------------------------------------------------------
__global__ __launch_bounds__(256) void k_packA(const float* __restrict__ q,
                                               char* __restrict__ wsb)
{
    int blk = blockIdx.x;            // dir*512 + b*4 + tt
    int tt = blk & 3;
    int b = (blk >> 2) & 127;
    int dir = blk >> 9;
    int tid = threadIdx.x;
    int t = tt * 64 + (tid >> 2);
    int dpart = (tid & 3) * 64;
    const float* src = q + ((size_t)t * NB + b) * D2 + dir * HALF + dpart;
    size_t so = (((size_t)(dir * 128 + b)) << 16) + (size_t)t * 256 + dpart;
    __bf16* qhi = (__bf16*)(wsb + OFF_QHI) + so;
    __bf16* qlo = (__bf16*)(wsb + OFF_QLO) + so;
#pragma unroll
    for (int j = 0; j < 64; j += 8) {
        float4 v0 = *(const float4*)(src + j);
        float4 v1 = *(const float4*)(src + j + 4);
        uint h0 = pack2bf(v0.x, v0.y), h1 = pack2bf(v0.z, v0.w);
        uint h2 = pack2bf(v1.x, v1.y), h3 = pack2bf(v1.z, v1.w);
        *(uint4*)(qhi + j) = make_uint4(h0, h1, h2, h3);
        uint l0 = pack2bf(v0.x - __uint_as_float(h0 << 16),
                          v0.y - __uint_as_float(h0 & 0xffff0000u));
        uint l1 = pack2bf(v0.z - __uint_as_float(h1 << 16),
                          v0.w - __uint_as_float(h1 & 0xffff0000u));
        uint l2 = pack2bf(v1.x - __uint_as_float(h2 << 16),
                          v1.y - __uint_as_float(h2 & 0xffff0000u));
        uint l3 = pack2bf(v1.z - __uint_as_float(h3 << 16),
                          v1.w - __uint_as_float(h3 & 0xffff0000u));
        *(uint4*)(qlo + j) = make_uint4(l0, l1, l2, l3);
    }
}

// ---------------------------------------------------------------------------
// K_packT: QT[d][t] = Qhi[t][d] per (dir,b) slice. grid 256.
// ---------------------------------------------------------------------------
__global__ __launch_bounds__(256) void k_packT(char* __restrict__ wsb)
{
    int blk = blockIdx.x;  // dir*128+b
    const __bf16* qhi = (const __bf16*)(wsb + OFF_QHI) + ((size_t)blk << 16);
    __bf16* qt = (__bf16*)(wsb + OFF_QT) + ((size_t)blk << 16);
    __shared__ __align__(16) __bf16 tile[64 * 264];  // [d][t], stride 264
    int tid = threadIdx.x;
    for (int dt = 0; dt < 4; dt++) {
        {
            const __bf16* srow = qhi + (size_t)tid * 256 + dt * 64;
#pragma unroll
            for (int j0 = 0; j0 < 64; j0 += 8) {
                union { uint4 u; __bf16 h[8]; } v;
                v.u = *(const uint4*)(srow + j0);
#pragma unroll
                for (int j = 0; j < 8; j++) tile[(j0 + j) * 264 + tid] = v.h[j];
            }
        }
        __syncthreads();
        {
            int d = tid >> 2, tq = tid & 3;
            const uint4* srcl = (const uint4*)&tile[d * 264 + tq * 64];
            uint4* dst = (uint4*)(qt + (size_t)(dt * 64 + d) * 256 + tq * 64);
#pragma unroll
            for (int j = 0; j < 8; j++) dst[j] = srcl[j];
        }
        __syncthreads();
    }
}

// ---------------------------------------------------------------------------
// K1: m_full (out 0..15). Unchanged (passing).
// ---------------------------------------------------------------------------
__global__ __launch_bounds__(256) void k_full(const float* __restrict__ p,
                                              const float* __restrict__ q,
                                              const float* __restrict__ W,
                                              const float* __restrict__ ws,
                                              float* __restrict__ out)
{
    int blk = blockIdx.x;
    int bg = blk & 3;
    int s = (blk >> 2) & 255;
    int dir = blk >> 10;
    int tid = threadIdx.x;
    int b = bg * 32 + (tid >> 3);
    int l = tid & 7;
    int wi = dir;

    __shared__ float W2[8][HALF];
    for (int e = tid; e < 8 * HALF; e += 256) {
        int ll = e >> 8, d = e & (HALF - 1);
        float w = W[(size_t)(wi * 8 + ll) * HALF + d];
        W2[ll][d] = w * w;
    }
    __syncthreads();

    int qrow = dir ? 0 : (S - 1);
    const float* pr = p + ((size_t)s * NB + b) * D2 + dir * HALF;
    const float* qr = q + ((size_t)qrow * NB + b) * D2 + dir * HALF;
    float num = 0.f;
    for (int d4 = 0; d4 < HALF; d4 += 4) {
        float4 pv = *(const float4*)(pr + d4);
        float4 qv = *(const float4*)(qr + d4);
        num += pv.x * qv.x * W2[l][d4] + pv.y * qv.y * W2[l][d4 + 1]
             + pv.z * qv.z * W2[l][d4 + 2] + pv.w * qv.w * W2[l][d4 + 3];
    }
    const float* normP = ws;
    const float* normQ = ws + NORM_ELEMS;
    float n1 = normP[normIdx(dir, l, b, s)];
    float n2 = normQ[normIdx(dir, l, b, qrow)];
    out[((size_t)s * NB + b) * 64 + dir * 8 + l] = num / fmaxf(n1 * n2, EPSF);
}

// ---------------------------------------------------------------------------
// K2: maxpool, bf16 MFMA, 2 l per block, k-chunk 32, B from Qhi ws (copy only).
// grid 4096. LDS 37.4 KB -> 3 blocks/CU (VGPR-capped).
// ---------------------------------------------------------------------------
__global__ __launch_bounds__(256) void k_maxpool3(const float* __restrict__ p,
                                                  const float* __restrict__ W,
                                                  const char* __restrict__ wsb,
                                                  float* __restrict__ out)
{
    int grp = blockIdx.x & 255;
    int sub = blockIdx.x >> 8;
    int b = grp & 127, dir = grp >> 7;
    int lp = sub >> 2, sc = sub & 3;
    int l0 = lp * 2;
    int s0 = sc * 64;
    int wi = 2 + dir;
    int tid = threadIdx.x;

    __shared__ __align__(16) __bf16 Al[2][64][40];
    __shared__ __align__(16) __bf16 Bl[256][40];
    __shared__ __align__(16) float W2L[2][HALF];
    __shared__ float n1l[2][64];
    __shared__ float n2l[2][HALF];
    __shared__ float wmax[2][4][64];

    const float* normP = (const float*)wsb;
    const float* normQ = normP + NORM_ELEMS;
    const __bf16* qh = (const __bf16*)(wsb + OFF_QHI) + ((size_t)(dir * 128 + b) << 16);

    {
        int e = tid;
#pragma unroll
        for (int ll = 0; ll < 2; ll++) {
            float w = W[(size_t)(wi * 8 + l0 + ll) * HALF + e];
            W2L[ll][e] = w * w;
            n2l[ll][e] = normQ[normIdx(dir, 8 + l0 + ll, b, e)];
        }
    }
    if (tid < 64) {
#pragma unroll
        for (int ll = 0; ll < 2; ll++)
            n1l[ll][tid] = normP[normIdx(dir, 8 + l0 + ll, b, s0 + tid)];
    }

    int wave = tid >> 6, lane = tid & 63;
    int colq = lane & 15, quad = lane >> 4;

    f32x4 acc[2][4][4];
#pragma unroll
    for (int ll = 0; ll < 2; ll++)
#pragma unroll
        for (int mi = 0; mi < 4; mi++)
#pragma unroll
            for (int ni = 0; ni < 4; ni++)
#pragma unroll
                for (int k = 0; k < 4; k++) acc[ll][mi][ni][k] = 0.f;

    const float* pbase = p + (size_t)b * D2 + dir * HALF;

    for (int k0 = 0; k0 < HALF; k0 += 32) {
        __syncthreads();
        // B: copy Qhi rows (row = tid, 32 cols)
        {
            const uint4* src = (const uint4*)(qh + (size_t)tid * 256 + k0);
            uint4* dst = (uint4*)&Bl[tid][0];
            dst[0] = src[0]; dst[1] = src[1]; dst[2] = src[2]; dst[3] = src[3];
        }
        // A: p fp32 * w^2 -> bf16, both l
        {
            int row = tid >> 2, cg = (tid & 3) * 8;
            const float* pr = pbase + (size_t)(s0 + row) * NBD2 + k0 + cg;
            float4 v0 = *(const float4*)pr;
            float4 v1 = *(const float4*)(pr + 4);
#pragma unroll
            for (int ll = 0; ll < 2; ll++) {
                float4 w0 = *(const float4*)&W2L[ll][k0 + cg];
                float4 w1 = *(const float4*)&W2L[ll][k0 + cg + 4];
                uint u0 = pack2bf(v0.x * w0.x, v0.y * w0.y);
                uint u1 = pack2bf(v0.z * w0.z, v0.w * w0.w);
                uint u2 = pack2bf(v1.x * w1.x, v1.y * w1.y);
                uint u3 = pack2bf(v1.z * w1.z, v1.w * w1.w);
                *(uint4*)&Al[ll][row][cg] = make_uint4(u0, u1, u2, u3);
            }
        }
        __syncthreads();
        {
            int kk = quad * 8;
            bf16x8 bfr[4];
#pragma unroll
            for (int ni = 0; ni < 4; ni++)
                bfr[ni] = *(const bf16x8*)&Bl[wave * 64 + ni * 16 + colq][kk];
#pragma unroll
            for (int ll = 0; ll < 2; ll++) {
                bf16x8 afl[4];
#pragma unroll
                for (int mi = 0; mi < 4; mi++)
                    afl[mi] = *(const bf16x8*)&Al[ll][mi * 16 + colq][kk];
#pragma unroll
                for (int mi = 0; mi < 4; mi++)
#pragma unroll
                    for (int ni = 0; ni < 4; ni++)
                        acc[ll][mi][ni] = __builtin_amdgcn_mfma_f32_16x16x32_bf16(
                            afl[mi], bfr[ni], acc[ll][mi][ni], 0, 0, 0);
            }
        }
    }

#pragma unroll
    for (int ll = 0; ll < 2; ll++) {
#pragma unroll
        for (int mi = 0; mi < 4; mi++) {
#pragma unroll
            for (int rg = 0; rg < 4; rg++) {
                int sl = mi * 16 + quad * 4 + rg;
                float n1v = n1l[ll][sl];
                float m = -3.4e38f;
#pragma unroll
                for (int ni = 0; ni < 4; ni++) {
                    int t = wave * 64 + ni * 16 + colq;
                    float sim = acc[ll][mi][ni][rg] / fmaxf(n1v * n2l[ll][t], EPSF);
                    m = fmaxf(m, sim);
                }
#pragma unroll
                for (int msk = 1; msk < 16; msk <<= 1)
                    m = fmaxf(m, __shfl_xor(m, msk, 64));
                if (colq == 0) wmax[ll][wave][sl] = m;
            }
        }
    }
    __syncthreads();
    if (tid < 128) {
        int ll = tid >> 6, sl = tid & 63;
        float m = fmaxf(fmaxf(wmax[ll][0][sl], wmax[ll][1][sl]),
                        fmaxf(wmax[ll][2][sl], wmax[ll][3][sl]));
        out[((size_t)(s0 + sl) * NB + b) * 64 + 16 + dir * 8 + l0 + ll] = m;
    }
}

// ---------------------------------------------------------------------------
// K_alpha: alpha = cos(p,q) per (dir,b), 64-s chunk; split-bf16 (3 MFMAs).
// Writes alpha bf16, asum f32, aidx i32 to ws. grid 1024. LDS 49.2 KB.
// ---------------------------------------------------------------------------
__global__ __launch_bounds__(256) void k_alpha(const float* __restrict__ p,
                                               char* __restrict__ wsb)
{
    int blk = blockIdx.x;
    int grp = blk & 255;
    int st = blk >> 8;
    int b = grp & 127, dir = grp >> 7;
    int s0 = st * 64;
    int tid = threadIdx.x;
    int wave = tid >> 6, lane = tid & 63;
    int colq = lane & 15, quad = lane >> 4;

    const float* normP = (const float*)wsb;
    const float* normQ = normP + NORM_ELEMS;
    size_t slice = (size_t)(dir * 128 + b) << 16;
    const __bf16* qh = (const __bf16*)(wsb + OFF_QHI) + slice;
    const __bf16* ql = (const __bf16*)(wsb + OFF_QLO) + slice;
    __bf16* aW = (__bf16*)(wsb + OFF_ALPHA) + slice;
    float* asumW = (float*)(wsb + OFF_ASUM) + (size_t)(dir * 128 + b) * 256;
    int* aidxW = (int*)(wsb + OFF_AIDX) + (size_t)(dir * 128 + b) * 256;

    __shared__ __align__(16) __bf16 QhiL[256][36];
    __shared__ __align__(16) __bf16 QloL[256][36];
    __shared__ __align__(16) __bf16 PhiL[64][36];
    __shared__ __align__(16) __bf16 PloL[64][36];
    __shared__ float redS[4][64];
    __shared__ float redM[4][64];
    __shared__ int   redI[4][64];

    const float* pbase = p + (size_t)b * D2 + dir * HALF;

    f32x4 acc[4][4];
#pragma unroll
    for (int mi = 0; mi < 4; mi++)
#pragma unroll
        for (int ni = 0; ni < 4; ni++)
#pragma unroll
            for (int k = 0; k < 4; k++) acc[mi][ni][k] = 0.f;

    for (int k0 = 0; k0 < HALF; k0 += 32) {
        __syncthreads();
        // Q: copy hi+lo (row = tid, 32 cols); 8B stores (stride 36 elts = 72B)
        {
            const uint4* sh = (const uint4*)(qh + (size_t)tid * 256 + k0);
            const uint4* sl_ = (const uint4*)(ql + (size_t)tid * 256 + k0);
            uint2* dh = (uint2*)&QhiL[tid][0];
            uint2* dl = (uint2*)&QloL[tid][0];
#pragma unroll
            for (int j = 0; j < 4; j++) {
                uint4 v = sh[j];
                dh[2 * j] = make_uint2(v.x, v.y);
                dh[2 * j + 1] = make_uint2(v.z, v.w);
                uint4 w = sl_[j];
                dl[2 * j] = make_uint2(w.x, w.y);
                dl[2 * j + 1] = make_uint2(w.z, w.w);
            }
        }
        // P: split fp32 on the fly (row = tid>>2, 8 cols)
        {
            int row = tid >> 2, cg = (tid & 3) * 8;
            const float* pr = pbase + (size_t)(s0 + row) * NBD2 + k0 + cg;
            float4 v0 = *(const float4*)pr;
            float4 v1 = *(const float4*)(pr + 4);
            uint h0 = pack2bf(v0.x, v0.y), h1 = pack2bf(v0.z, v0.w);
            uint h2 = pack2bf(v1.x, v1.y), h3 = pack2bf(v1.z, v1.w);
            uint l0 = pack2bf(v0.x - __uint_as_float(h0 << 16),
                              v0.y - __uint_as_float(h0 & 0xffff0000u));
            uint l1 = pack2bf(v0.z - __uint_as_float(h1 << 16),
                              v0.w - __uint_as_float(h1 & 0xffff0000u));
            uint l2 = pack2bf(v1.x - __uint_as_float(h2 << 16),
                              v1.y - __uint_as_float(h2 & 0xffff0000u));
            uint l3 = pack2bf(v1.z - __uint_as_float(h3 << 16),
                              v1.w - __uint_as_float(h3 & 0xffff0000u));
            uint2* dh = (uint2*)&PhiL[row][cg];
            uint2* dl = (uint2*)&PloL[row][cg];
            dh[0] = make_uint2(h0, h1); dh[1] = make_uint2(h2, h3);
            dl[0] = make_uint2(l0, l1); dl[1] = make_uint2(l2, l3);
        }
        __syncthreads();
        {
            int kk = quad * 8;
            bf16x8 ah[4], al_[4], bh[4], bl_[4];
#pragma unroll
            for (int mi = 0; mi < 4; mi++) {
                ah[mi] = ld8(&PhiL[mi * 16 + colq][kk]);
                al_[mi] = ld8(&PloL[mi * 16 + colq][kk]);
            }
#pragma unroll
            for (int ni = 0; ni < 4; ni++) {
                bh[ni] = ld8(&QhiL[wave * 64 + ni * 16 + colq][kk]);
                bl_[ni] = ld8(&QloL[wave * 64 + ni * 16 + colq][kk]);
            }
#pragma unroll
            for (int mi = 0; mi < 4; mi++)
#pragma unroll
                for (int ni = 0; ni < 4; ni++) {
                    acc[mi][ni] = __builtin_amdgcn_mfma_f32_16x16x32_bf16(
                        ah[mi], bh[ni], acc[mi][ni], 0, 0, 0);
                    acc[mi][ni] = __builtin_amdgcn_mfma_f32_16x16x32_bf16(
                        ah[mi], bl_[ni], acc[mi][ni], 0, 0, 0);
                    acc[mi][ni] = __builtin_amdgcn_mfma_f32_16x16x32_bf16(
                        al_[mi], bh[ni], acc[mi][ni], 0, 0, 0);
                }
        }
    }

    // normalize, write alpha bf16 to ws, reduce sum/argmax
    float nqv[4];
#pragma unroll
    for (int ni = 0; ni < 4; ni++)
        nqv[ni] = normQ[normIdx(dir, 32, b, wave * 64 + ni * 16 + colq)];

#pragma unroll
    for (int mi = 0; mi < 4; mi++) {
        int rowbase = mi * 16 + quad * 4;
        float npa[4];
#pragma unroll
        for (int rg = 0; rg < 4; rg++)
            npa[rg] = normP[normIdx(dir, 32, b, s0 + rowbase + rg)];
        float av[4][4];
#pragma unroll
        for (int ni = 0; ni < 4; ni++)
#pragma unroll
            for (int rg = 0; rg < 4; rg++)
                av[ni][rg] = acc[mi][ni][rg] / fmaxf(npa[rg] * nqv[ni], EPSF);
#pragma unroll
        for (int ni = 0; ni < 4; ni++)
#pragma unroll
            for (int rg = 0; rg < 4; rg++)
                aW[(size_t)(s0 + rowbase + rg) * 256 + wave * 64 + ni * 16 + colq] =
                    (__bf16)av[ni][rg];
#pragma unroll
        for (int rg = 0; rg < 4; rg++) {
            float sm = av[0][rg] + av[1][rg] + av[2][rg] + av[3][rg];
            float mx = av[0][rg];
            int ix = wave * 64 + colq;
#pragma unroll
            for (int ni = 1; ni < 4; ni++) {
                if (av[ni][rg] > mx) { mx = av[ni][rg]; ix = wave * 64 + ni * 16 + colq; }
            }
#pragma unroll
            for (int off = 1; off < 16; off <<= 1) {
                sm += __shfl_xor(sm, off, 64);
                float m2 = __shfl_xor(mx, off, 64);
                int i2 = __shfl_xor(ix, off, 64);
                if (m2 > mx || (m2 == mx && i2 < ix)) { mx = m2; ix = i2; }
            }
            if (colq == 0) {
                redS[wave][rowbase + rg] = sm;
                redM[wave][rowbase + rg] = mx;
                redI[wave][rowbase + rg] = ix;
            }
        }
    }
    __syncthreads();
    if (tid < 64) {
        float sm = redS[0][tid] + redS[1][tid] + redS[2][tid] + redS[3][tid];
        float mx = redM[0][tid];
        int ix = redI[0][tid];
#pragma unroll
        for (int w = 1; w < 4; w++) {
            float m2 = redM[w][tid];
            int i2 = redI[w][tid];
            if (m2 > mx || (m2 == mx && i2 < ix)) { mx = m2; ix = i2; }
        }
        asumW[s0 + tid] = sm;
        aidxW[s0 + tid] = ix;
    }
}

// ---------------------------------------------------------------------------
// K_hout: h = alpha . q (bf16 MFMA from alpha ws + QT ws), then E-GEMM epilogue.
// grid 1024. LDS 46.6 KB -> 3 blocks/CU.
// ---------------------------------------------------------------------------
__global__ __launch_bounds__(256) void k_hout(const float* __restrict__ p,
                                              const float* __restrict__ W,
                                              char* __restrict__ wsb,
                                              float* __restrict__ out)
{
    int blk = blockIdx.x;
    int grp = blk & 255;
    int st = blk >> 8;
    int b = grp & 127, dir = grp >> 7;
    int s0 = st * 64;
    int tid = threadIdx.x;
    int wave = tid >> 6, lane = tid & 63;
    int colq = lane & 15, quad = lane >> 4;

    const float* normP = (const float*)wsb;
    const float* normQ = normP + NORM_ELEMS;
    size_t slice = (size_t)(dir * 128 + b) << 16;
    const __bf16* qh = (const __bf16*)(wsb + OFF_QHI) + slice;
    const __bf16* qt = (const __bf16*)(wsb + OFF_QT) + slice;
    const __bf16* aW = (const __bf16*)(wsb + OFF_ALPHA) + slice;
    const float* asumW = (const float*)(wsb + OFF_ASUM) + (size_t)(dir * 128 + b) * 256;
    const int* aidxW = (const int*)(wsb + OFF_AIDX) + (size_t)(dir * 128 + b) * 256;

    __shared__ __align__(16) char reg0[46080];
    __bf16* alphaA = (__bf16*)reg0;              // [64][72]
    __bf16* QTl = alphaA + 64 * 72;              // [256][72]
    __bf16* E = (__bf16*)reg0;                   // [64][264]
    __bf16* W45 = E + 64 * 264;                  // [16][264]
    __shared__ int   aidxL[64];
    __shared__ float asumL[64];

    if (tid < 64) { aidxL[tid] = aidxW[s0 + tid]; asumL[tid] = asumW[s0 + tid]; }

    const float* pbase = p + (size_t)b * D2 + dir * HALF;

    f32x4 acc[4][4];
#pragma unroll
    for (int mi = 0; mi < 4; mi++)
#pragma unroll
        for (int ni = 0; ni < 4; ni++)
#pragma unroll
            for (int k = 0; k < 4; k++) acc[mi][ni][k] = 0.f;

    // phase 3: h[s][d] = sum_t alpha[s][t] q[t][d]; K = t, 4 chunks of 64
    for (int tc = 0; tc < 4; tc++) {
        __syncthreads();
        {
            int row = tid >> 2, cp = (tid & 3) * 16;
            const uint4* src = (const uint4*)(aW + (size_t)(s0 + row) * 256 + tc * 64 + cp);
            uint4* dst = (uint4*)&alphaA[row * 72 + cp];
            dst[0] = src[0]; dst[1] = src[1];
        }
        {
            const uint4* src = (const uint4*)(qt + (size_t)tid * 256 + tc * 64);
            uint4* dst = (uint4*)&QTl[tid * 72];
#pragma unroll
            for (int j = 0; j < 8; j++) dst[j] = src[j];
        }
        __syncthreads();
#pragma unroll
        for (int step = 0; step < 2; step++) {
            int kk = step * 32 + quad * 8;
            bf16x8 af[4], bfr[4];
#pragma unroll
            for (int mi = 0; mi < 4; mi++)
                af[mi] = *(const bf16x8*)&alphaA[(mi * 16 + colq) * 72 + kk];
#pragma unroll
            for (int ni = 0; ni < 4; ni++)
                bfr[ni] = *(const bf16x8*)&QTl[(wave * 64 + ni * 16 + colq) * 72 + kk];
#pragma unroll
            for (int mi = 0; mi < 4; mi++)
#pragma unroll
                for (int ni = 0; ni < 4; ni++)
                    acc[mi][ni] = __builtin_amdgcn_mfma_f32_16x16x32_bf16(
                        af[mi], bfr[ni], acc[mi][ni], 0, 0, 0);
        }
    }

    // epilogue: E-GEMMs vs [W4^2; W5^2]
    __syncthreads();
    {
        int n = tid >> 4, dblk = (tid & 15) * 16;
        int wrow = (n < 8) ? (4 * 8 + n) : (5 * 8 + (n - 8));
        const float* wr = W + (size_t)wrow * HALF + dblk;
        float4 a = *(const float4*)wr;
        float4 bq = *(const float4*)(wr + 4);
        float4 c = *(const float4*)(wr + 8);
        float4 d4 = *(const float4*)(wr + 12);
        uint u0 = pack2bf(a.x * a.x, a.y * a.y), u1 = pack2bf(a.z * a.z, a.w * a.w);
        uint u2 = pack2bf(bq.x * bq.x, bq.y * bq.y), u3 = pack2bf(bq.z * bq.z, bq.w * bq.w);
        uint u4 = pack2bf(c.x * c.x, c.y * c.y), u5 = pack2bf(c.z * c.z, c.w * c.w);
        uint u6 = pack2bf(d4.x * d4.x, d4.y * d4.y), u7 = pack2bf(d4.z * d4.z, d4.w * d4.w);
        uint4* dst = (uint4*)&W45[n * 264 + dblk];
        dst[0] = make_uint4(u0, u1, u2, u3);
        dst[1] = make_uint4(u4, u5, u6, u7);
    }

    f32x4 c1, c2, c3;
#pragma unroll
    for (int k = 0; k < 4; k++) { c1[k] = 0.f; c2[k] = 0.f; c3[k] = 0.f; }

    // E1 = p .* h
#pragma unroll
    for (int mi = 0; mi < 4; mi++)
#pragma unroll
        for (int rg = 0; rg < 4; rg++) {
            int sl = mi * 16 + quad * 4 + rg;
            const float* prow = pbase + (size_t)(s0 + sl) * NBD2;
#pragma unroll
            for (int ni = 0; ni < 4; ni++) {
                int d = wave * 64 + ni * 16 + colq;
                E[sl * 264 + d] = (__bf16)(prow[d] * acc[mi][ni][rg]);
            }
        }
    __syncthreads();
#pragma unroll
    for (int step = 0; step < 8; step++) {
        int kk = step * 32 + quad * 8;
        bf16x8 ea = *(const bf16x8*)&E[(wave * 16 + colq) * 264 + kk];
        bf16x8 wb = *(const bf16x8*)&W45[colq * 264 + kk];
        c1 = __builtin_amdgcn_mfma_f32_16x16x32_bf16(ea, wb, c1, 0, 0, 0);
    }
    __syncthreads();

    // E2 = h .* h
#pragma unroll
    for (int mi = 0; mi < 4; mi++)
#pragma unroll
        for (int rg = 0; rg < 4; rg++) {
            int sl = mi * 16 + quad * 4 + rg;
#pragma unroll
            for (int ni = 0; ni < 4; ni++) {
                int d = wave * 64 + ni * 16 + colq;
                float hv = acc[mi][ni][rg];
                E[sl * 264 + d] = (__bf16)(hv * hv);
            }
        }
    __syncthreads();
#pragma unroll
    for (int step = 0; step < 8; step++) {
        int kk = step * 32 + quad * 8;
        bf16x8 ea = *(const bf16x8*)&E[(wave * 16 + colq) * 264 + kk];
        bf16x8 wb = *(const bf16x8*)&W45[colq * 264 + kk];
        c2 = __builtin_amdgcn_mfma_f32_16x16x32_bf16(ea, wb, c2, 0, 0, 0);
    }
    __syncthreads();

    // E3 = p .* q[aidx]
#pragma unroll
    for (int mi = 0; mi < 4; mi++)
#pragma unroll
        for (int rg = 0; rg < 4; rg++) {
            int sl = mi * 16 + quad * 4 + rg;
            const float* prow = pbase + (size_t)(s0 + sl) * NBD2;
            const __bf16* qrow = qh + (size_t)aidxL[sl] * 256;
#pragma unroll
            for (int ni = 0; ni < 4; ni++) {
                int d = wave * 64 + ni * 16 + colq;
                E[sl * 264 + d] = (__bf16)(prow[d] * (float)qrow[d]);
            }
        }
    __syncthreads();
#pragma unroll
    for (int step = 0; step < 8; step++) {
        int kk = step * 32 + quad * 8;
        bf16x8 ea = *(const bf16x8*)&E[(wave * 16 + colq) * 264 + kk];
        bf16x8 wb = *(const bf16x8*)&W45[colq * 264 + kk];
        c3 = __builtin_amdgcn_mfma_f32_16x16x32_bf16(ea, wb, c3, 0, 0, 0);
    }

    // write out: rows s = wave*16 + quad*4 + rg, col n = colq
#pragma unroll
    for (int rg = 0; rg < 4; rg++) {
        int sl = wave * 16 + quad * 4 + rg;
        size_t ob = ((size_t)(s0 + sl) * NB + b) * 64;
        if (colq < 8) {
            int l = colq;
            float np4 = normP[normIdx(dir, 16 + l, b, s0 + sl)];
            float nh = sqrtf(fmaxf(c2[rg], 0.f));
            float sgn = (asumL[sl] < 0.f) ? -1.f : 1.f;
            out[ob + 32 + dir * 8 + l] = sgn * c1[rg] / fmaxf(np4 * nh, EPSF);
        } else {
            int l = colq - 8;
            float np5 = normP[normIdx(dir, 24 + l, b, s0 + sl)];
            float nq5 = normQ[normIdx(dir, 24 + l, b, aidxL[sl])];
            out[ob + 48 + dir * 8 + l] = c3[rg] / fmaxf(np5 * nq5, EPSF);
        }
    }
}

// ---------------------------------------------------------------------------
extern "C" void kernel_launch(void* const* d_in, const int* in_sizes, int n_in,
                              void* d_out, int out_size, void* d_ws, size_t ws_size,
                              hipStream_t stream)
{
    (void)in_sizes; (void)n_in; (void)out_size;
    if (ws_size < WS_NEED) return;  // clean, deterministic failure if ws too small
    const float* p = (const float*)d_in[0];
    const float* q = (const float*)d_in[1];
    const float* W = (const float*)d_in[2];
    float* out = (float*)d_out;
    float* ws = (float*)d_ws;
    char* wsb = (char*)d_ws;

    hipLaunchKernelGGL(k_norms, dim3(512), dim3(256), 0, stream, p, q, W, ws);
    hipLaunchKernelGGL(k_packA, dim3(1024), dim3(256), 0, stream, q, wsb);
    hipLaunchKernelGGL(k_packT, dim3(256), dim3(256), 0, stream, wsb);
    hipLaunchKernelGGL(k_full, dim3(2048), dim3(256), 0, stream, p, q, W, ws, out);
    hipLaunchKernelGGL(k_maxpool3, dim3(4096), dim3(256), 0, stream, p, W, wsb, out);
    hipLaunchKernelGGL(k_alpha, dim3(1024), dim3(256), 0, stream, p, wsb);
    hipLaunchKernelGGL(k_hout, dim3(1024), dim3(256), 0, stream, p, W, wsb, out);
}

// Round 4
// 844.587 us; speedup vs baseline: 1.3617x; 1.0301x over previous
//
#include <hip/hip_runtime.h>
#include <hip/hip_bf16.h>

#define EPSF 1e-8f

typedef __attribute__((ext_vector_type(8))) __bf16 bf16x8;
typedef __attribute__((ext_vector_type(4))) float f32x4;

constexpr int S = 256;
constexpr int NB = 128;
constexpr int D2 = 512;
constexpr int HALF = 256;
constexpr int NBD2 = NB * D2;
constexpr size_t NORM_ELEMS = (size_t)2 * 33 * NB * S;  // per tensor (p or q)

// ws byte offsets
constexpr size_t OFF_ASUM  = 17301504;   // f32 [2*128*256]
constexpr size_t OFF_AIDX  = 17563648;   // i32 [2*128*256]
constexpr size_t OFF_QHI   = 17825792;   // bf16 [2*128][256 t][256 d]
constexpr size_t OFF_QLO   = 51380224;   // bf16 same
constexpr size_t OFF_QT    = 84934656;   // bf16 [2*128][256 d][256 t]
constexpr size_t OFF_ALPHA = 118489088;  // bf16 [2*128][256 s][256 t]
constexpr size_t WS_NEED   = 152043520;

__device__ __forceinline__ size_t normIdx(int dir, int slot, int b, int row) {
    return (((size_t)dir * 33 + slot) * NB + b) * S + row;
}

__device__ __forceinline__ uint pack2bf(float a, float b) {
    __hip_bfloat162 t = __float22bfloat162_rn(make_float2(a, b));
    uint u;
    __builtin_memcpy(&u, &t, 4);
    return u;
}

__device__ __forceinline__ bf16x8 ld8(const __bf16* p8) {  // 8-byte-aligned load
    union { uint2 u[2]; bf16x8 v; } t;
    t.u[0] = *(const uint2*)p8;
    t.u[1] = *(const uint2*)(p8 + 4);
    return t.v;
}

__device__ __forceinline__ void st16_u2(__bf16* dst, uint4 v) {  // 16 B via 2x b64
    *(uint2*)dst = make_uint2(v.x, v.y);
    *(uint2*)(dst + 4) = make_uint2(v.z, v.w);
}

// ---------------------------------------------------------------------------
// K0: all weighted norms.  grid = 2(tensor) * 2(dir) * 128(b), block = 256
// ---------------------------------------------------------------------------
__global__ __launch_bounds__(256) void k_norms(const float* __restrict__ p,
                                               const float* __restrict__ q,
                                               const float* __restrict__ W,
                                               float* __restrict__ ws)
{
    int blk = blockIdx.x;
    int b = blk & 127;
    int dir = (blk >> 7) & 1;
    int tensor = blk >> 8;
    const float* x = tensor ? q : p;
    float* outN = ws + (size_t)tensor * NORM_ELEMS;

    __shared__ float W2[32][HALF];
    for (int e = threadIdx.x; e < 32 * HALF; e += 256) {
        int slot = e >> 8;
        int d = e & (HALF - 1);
        int wl = slot >> 3, l = slot & 7;
        int wi = (wl == 0) ? dir : (wl == 1) ? (2 + dir) : (wl == 2) ? 4 : 5;
        float w = W[(size_t)(wi * 8 + l) * HALF + d];
        W2[slot][d] = w * w;
    }
    __syncthreads();

    int row = threadIdx.x;
    const float* xr = x + ((size_t)row * NB + b) * D2 + dir * HALF;
    float acc[33];
#pragma unroll
    for (int i = 0; i < 33; i++) acc[i] = 0.f;
    for (int d4 = 0; d4 < HALF; d4 += 4) {
        float4 v = *(const float4*)(xr + d4);
        float xx = v.x * v.x, yy = v.y * v.y, zz = v.z * v.z, ww = v.w * v.w;
        acc[32] += xx + yy + zz + ww;
#pragma unroll
        for (int slot = 0; slot < 32; slot++) {
            acc[slot] += xx * W2[slot][d4] + yy * W2[slot][d4 + 1]
                       + zz * W2[slot][d4 + 2] + ww * W2[slot][d4 + 3];
        }
    }
#pragma unroll
    for (int slot = 0; slot < 33; slot++)
        outN[normIdx(dir, slot, b, row)] = sqrtf(acc[slot]);
}

// ---------------------------------------------------------------------------
// K_packA: Qhi = rne_bf16(q), Qlo = rne_bf16(q - Qhi). grid 1024.
// ---------------------------------------------------------------------------
__global__ __launch_bounds__(256) void k_packA(const float* __restrict__ q,
                                               char* __restrict__ wsb)
{
    int blk = blockIdx.x;            // dir*512 + b*4 + tt
    int tt = blk & 3;
    int b = (blk >> 2) & 127;
    int dir = blk >> 9;
    int tid = threadIdx.x;
    int t = tt * 64 + (tid >> 2);
    int dpart = (tid & 3) * 64;
    const float* src = q + ((size_t)t * NB + b) * D2 + dir * HALF + dpart;
    size_t so = (((size_t)(dir * 128 + b)) << 16) + (size_t)t * 256 + dpart;
    __bf16* qhi = (__bf16*)(wsb + OFF_QHI) + so;
    __bf16* qlo = (__bf16*)(wsb + OFF_QLO) + so;
#pragma unroll
    for (int j = 0; j < 64; j += 8) {
        float4 v0 = *(const float4*)(src + j);
        float4 v1 = *(const float4*)(src + j + 4);
        uint h0 = pack2bf(v0.x, v0.y), h1 = pack2bf(v0.z, v0.w);
        uint h2 = pack2bf(v1.x, v1.y), h3 = pack2bf(v1.z, v1.w);
        *(uint4*)(qhi + j) = make_uint4(h0, h1, h2, h3);
        uint l0 = pack2bf(v0.x - __uint_as_float(h0 << 16),
                          v0.y - __uint_as_float(h0 & 0xffff0000u));
        uint l1 = pack2bf(v0.z - __uint_as_float(h1 << 16),
                          v0.w - __uint_as_float(h1 & 0xffff0000u));
        uint l2 = pack2bf(v1.x - __uint_as_float(h2 << 16),
                          v1.y - __uint_as_float(h2 & 0xffff0000u));
        uint l3 = pack2bf(v1.z - __uint_as_float(h3 << 16),
                          v1.w - __uint_as_float(h3 & 0xffff0000u));
        *(uint4*)(qlo + j) = make_uint4(l0, l1, l2, l3);
    }
}

// ---------------------------------------------------------------------------
// K_packT: QT[d][t] = Qhi[t][d] per (dir,b) slice. grid 256.
// ---------------------------------------------------------------------------
__global__ __launch_bounds__(256) void k_packT(char* __restrict__ wsb)
{
    int blk = blockIdx.x;  // dir*128+b
    const __bf16* qhi = (const __bf16*)(wsb + OFF_QHI) + ((size_t)blk << 16);
    __bf16* qt = (__bf16*)(wsb + OFF_QT) + ((size_t)blk << 16);
    __shared__ __align__(16) __bf16 tile[64 * 264];  // [d][t], stride 264
    int tid = threadIdx.x;
    for (int dt = 0; dt < 4; dt++) {
        {
            const __bf16* srow = qhi + (size_t)tid * 256 + dt * 64;
#pragma unroll
            for (int j0 = 0; j0 < 64; j0 += 8) {
                union { uint4 u; __bf16 h[8]; } v;
                v.u = *(const uint4*)(srow + j0);
#pragma unroll
                for (int j = 0; j < 8; j++) tile[(j0 + j) * 264 + tid] = v.h[j];
            }
        }
        __syncthreads();
        {
            int d = tid >> 2, tq = tid & 3;
            const uint4* srcl = (const uint4*)&tile[d * 264 + tq * 64];
            uint4* dst = (uint4*)(qt + (size_t)(dt * 64 + d) * 256 + tq * 64);
#pragma unroll
            for (int j = 0; j < 8; j++) dst[j] = srcl[j];
        }
        __syncthreads();
    }
}

// ---------------------------------------------------------------------------
// K1: m_full (out 0..15). Unchanged (passing).
// ---------------------------------------------------------------------------
__global__ __launch_bounds__(256) void k_full(const float* __restrict__ p,
                                              const float* __restrict__ q,
                                              const float* __restrict__ W,
                                              const float* __restrict__ ws,
                                              float* __restrict__ out)
{
    int blk = blockIdx.x;
    int bg = blk & 3;
    int s = (blk >> 2) & 255;
    int dir = blk >> 10;
    int tid = threadIdx.x;
    int b = bg * 32 + (tid >> 3);
    int l = tid & 7;
    int wi = dir;

    __shared__ float W2[8][HALF];
    for (int e = tid; e < 8 * HALF; e += 256) {
        int ll = e >> 8, d = e & (HALF - 1);
        float w = W[(size_t)(wi * 8 + ll) * HALF + d];
        W2[ll][d] = w * w;
    }
    __syncthreads();

    int qrow = dir ? 0 : (S - 1);
    const float* pr = p + ((size_t)s * NB + b) * D2 + dir * HALF;
    const float* qr = q + ((size_t)qrow * NB + b) * D2 + dir * HALF;
    float num = 0.f;
    for (int d4 = 0; d4 < HALF; d4 += 4) {
        float4 pv = *(const float4*)(pr + d4);
        float4 qv = *(const float4*)(qr + d4);
        num += pv.x * qv.x * W2[l][d4] + pv.y * qv.y * W2[l][d4 + 1]
             + pv.z * qv.z * W2[l][d4 + 2] + pv.w * qv.w * W2[l][d4 + 3];
    }
    const float* normP = ws;
    const float* normQ = ws + NORM_ELEMS;
    float n1 = normP[normIdx(dir, l, b, s)];
    float n2 = normQ[normIdx(dir, l, b, qrow)];
    out[((size_t)s * NB + b) * 64 + dir * 8 + l] = num / fmaxf(n1 * n2, EPSF);
}

// ---------------------------------------------------------------------------
// K2: maxpool, bf16 MFMA, 2 l per block, k-chunk 32.
// Stride-36 LDS rows (bank-conflict-free b64 class) + register double-pump
// prefetch (global loads for chunk k+1 issued before MFMA of chunk k).
// grid 4096.
// ---------------------------------------------------------------------------
__global__ __launch_bounds__(256) void k_maxpool4(const float* __restrict__ p,
                                                  const float* __restrict__ W,
                                                  const char* __restrict__ wsb,
                                                  float* __restrict__ out)
{
    int grp = blockIdx.x & 255;
    int sub = blockIdx.x >> 8;
    int b = grp & 127, dir = grp >> 7;
    int lp = sub >> 2, sc = sub & 3;
    int l0 = lp * 2;
    int s0 = sc * 64;
    int wi = 2 + dir;
    int tid = threadIdx.x;

    __shared__ __align__(16) __bf16 Al[2][64][36];   // stride 72 B: bank-free b64
    __shared__ __align__(16) __bf16 Bl[256][36];
    __shared__ __align__(16) float W2L[2][HALF];
    __shared__ float n1l[2][64];
    __shared__ float n2l[2][HALF];
    __shared__ float wmax[2][4][64];

    const float* normP = (const float*)wsb;
    const float* normQ = normP + NORM_ELEMS;
    const __bf16* qh = (const __bf16*)(wsb + OFF_QHI) + ((size_t)(dir * 128 + b) << 16);

    {
        int e = tid;
#pragma unroll
        for (int ll = 0; ll < 2; ll++) {
            float w = W[(size_t)(wi * 8 + l0 + ll) * HALF + e];
            W2L[ll][e] = w * w;
            n2l[ll][e] = normQ[normIdx(dir, 8 + l0 + ll, b, e)];
        }
    }
    if (tid < 64) {
#pragma unroll
        for (int ll = 0; ll < 2; ll++)
            n1l[ll][tid] = normP[normIdx(dir, 8 + l0 + ll, b, s0 + tid)];
    }

    int wave = tid >> 6, lane = tid & 63;
    int colq = lane & 15, quad = lane >> 4;
    int arow = tid >> 2, acg = (tid & 3) * 8;

    f32x4 acc[2][4][4];
#pragma unroll
    for (int ll = 0; ll < 2; ll++)
#pragma unroll
        for (int mi = 0; mi < 4; mi++)
#pragma unroll
            for (int ni = 0; ni < 4; ni++)
#pragma unroll
                for (int k = 0; k < 4; k++) acc[ll][mi][ni][k] = 0.f;

    const float* pbase = p + (size_t)b * D2 + dir * HALF;

    // prefetch registers
    uint4 breg[4];
    float4 av0, av1;
    {
        const uint4* src = (const uint4*)(qh + (size_t)tid * 256);
        breg[0] = src[0]; breg[1] = src[1]; breg[2] = src[2]; breg[3] = src[3];
        const float* pr = pbase + (size_t)(s0 + arow) * NBD2 + acg;
        av0 = *(const float4*)pr;
        av1 = *(const float4*)(pr + 4);
    }

    for (int kc = 0; kc < 8; kc++) {
        int k0 = kc * 32;
        __syncthreads();
        // store prefetched chunk to LDS
        {
            __bf16* dst = &Bl[tid][0];
            st16_u2(dst, breg[0]); st16_u2(dst + 8, breg[1]);
            st16_u2(dst + 16, breg[2]); st16_u2(dst + 24, breg[3]);
        }
        {
#pragma unroll
            for (int ll = 0; ll < 2; ll++) {
                float4 w0 = *(const float4*)&W2L[ll][k0 + acg];
                float4 w1 = *(const float4*)&W2L[ll][k0 + acg + 4];
                uint u0 = pack2bf(av0.x * w0.x, av0.y * w0.y);
                uint u1 = pack2bf(av0.z * w0.z, av0.w * w0.w);
                uint u2 = pack2bf(av1.x * w1.x, av1.y * w1.y);
                uint u3 = pack2bf(av1.z * w1.z, av1.w * w1.w);
                st16_u2(&Al[ll][arow][acg], make_uint4(u0, u1, u2, u3));
            }
        }
        __syncthreads();
        // issue next chunk's global loads (overlap with MFMA below)
        if (kc < 7) {
            int kn = k0 + 32;
            const uint4* src = (const uint4*)(qh + (size_t)tid * 256 + kn);
            breg[0] = src[0]; breg[1] = src[1]; breg[2] = src[2]; breg[3] = src[3];
            const float* pr = pbase + (size_t)(s0 + arow) * NBD2 + kn + acg;
            av0 = *(const float4*)pr;
            av1 = *(const float4*)(pr + 4);
        }
        {
            int kk = quad * 8;
            bf16x8 bfr[4];
#pragma unroll
            for (int ni = 0; ni < 4; ni++)
                bfr[ni] = ld8(&Bl[wave * 64 + ni * 16 + colq][kk]);
#pragma unroll
            for (int ll = 0; ll < 2; ll++) {
                bf16x8 afl[4];
#pragma unroll
                for (int mi = 0; mi < 4; mi++)
                    afl[mi] = ld8(&Al[ll][mi * 16 + colq][kk]);
#pragma unroll
                for (int mi = 0; mi < 4; mi++)
#pragma unroll
                    for (int ni = 0; ni < 4; ni++)
                        acc[ll][mi][ni] = __builtin_amdgcn_mfma_f32_16x16x32_bf16(
                            afl[mi], bfr[ni], acc[ll][mi][ni], 0, 0, 0);
            }
        }
    }

#pragma unroll
    for (int ll = 0; ll < 2; ll++) {
#pragma unroll
        for (int mi = 0; mi < 4; mi++) {
#pragma unroll
            for (int rg = 0; rg < 4; rg++) {
                int sl = mi * 16 + quad * 4 + rg;
                float n1v = n1l[ll][sl];
                float m = -3.4e38f;
#pragma unroll
                for (int ni = 0; ni < 4; ni++) {
                    int t = wave * 64 + ni * 16 + colq;
                    float sim = acc[ll][mi][ni][rg] / fmaxf(n1v * n2l[ll][t], EPSF);
                    m = fmaxf(m, sim);
                }
#pragma unroll
                for (int msk = 1; msk < 16; msk <<= 1)
                    m = fmaxf(m, __shfl_xor(m, msk, 64));
                if (colq == 0) wmax[ll][wave][sl] = m;
            }
        }
    }
    __syncthreads();
    if (tid < 128) {
        int ll = tid >> 6, sl = tid & 63;
        float m = fmaxf(fmaxf(wmax[ll][0][sl], wmax[ll][1][sl]),
                        fmaxf(wmax[ll][2][sl], wmax[ll][3][sl]));
        out[((size_t)(s0 + sl) * NB + b) * 64 + 16 + dir * 8 + l0 + ll] = m;
    }
}

// ---------------------------------------------------------------------------
// K_alpha: alpha = cos(p,q); split-bf16 (3 MFMAs); register double-pump.
// Writes alpha bf16, asum f32, aidx i32 to ws. grid 1024.
// ---------------------------------------------------------------------------
__global__ __launch_bounds__(256) void k_alpha(const float* __restrict__ p,
                                               char* __restrict__ wsb)
{
    int blk = blockIdx.x;
    int grp = blk & 255;
    int st = blk >> 8;
    int b = grp & 127, dir = grp >> 7;
    int s0 = st * 64;
    int tid = threadIdx.x;
    int wave = tid >> 6, lane = tid & 63;
    int colq = lane & 15, quad = lane >> 4;

    const float* normP = (const float*)wsb;
    const float* normQ = normP + NORM_ELEMS;
    size_t slice = (size_t)(dir * 128 + b) << 16;
    const __bf16* qh = (const __bf16*)(wsb + OFF_QHI) + slice;
    const __bf16* ql = (const __bf16*)(wsb + OFF_QLO) + slice;
    __bf16* aW = (__bf16*)(wsb + OFF_ALPHA) + slice;
    float* asumW = (float*)(wsb + OFF_ASUM) + (size_t)(dir * 128 + b) * 256;
    int* aidxW = (int*)(wsb + OFF_AIDX) + (size_t)(dir * 128 + b) * 256;

    __shared__ __align__(16) __bf16 QhiL[256][36];
    __shared__ __align__(16) __bf16 QloL[256][36];
    __shared__ __align__(16) __bf16 PhiL[64][36];
    __shared__ __align__(16) __bf16 PloL[64][36];
    __shared__ float redS[4][64];
    __shared__ float redM[4][64];
    __shared__ int   redI[4][64];

    const float* pbase = p + (size_t)b * D2 + dir * HALF;
    int prow_ = tid >> 2, pcg = (tid & 3) * 8;

    f32x4 acc[4][4];
#pragma unroll
    for (int mi = 0; mi < 4; mi++)
#pragma unroll
        for (int ni = 0; ni < 4; ni++)
#pragma unroll
            for (int k = 0; k < 4; k++) acc[mi][ni][k] = 0.f;

    uint4 qhR[2], qlR[2];
    float4 pv0, pv1;
    {
        const uint4* sh = (const uint4*)(qh + (size_t)tid * 256);
        const uint4* sl_ = (const uint4*)(ql + (size_t)tid * 256);
        qhR[0] = sh[0]; qhR[1] = sh[1];
        qlR[0] = sl_[0]; qlR[1] = sl_[1];
        // note: 32 cols = 4 uint4 per tensor; split across two pairs to cap regs
        const float* pr = pbase + (size_t)(s0 + prow_) * NBD2 + pcg;
        pv0 = *(const float4*)pr;
        pv1 = *(const float4*)(pr + 4);
    }
    uint4 qhR2[2], qlR2[2];
    {
        const uint4* sh = (const uint4*)(qh + (size_t)tid * 256);
        const uint4* sl_ = (const uint4*)(ql + (size_t)tid * 256);
        qhR2[0] = sh[2]; qhR2[1] = sh[3];
        qlR2[0] = sl_[2]; qlR2[1] = sl_[3];
    }

    for (int kc = 0; kc < 8; kc++) {
        int k0 = kc * 32;
        __syncthreads();
        // store Q hi/lo chunk
        {
            __bf16* dh = &QhiL[tid][0];
            __bf16* dl = &QloL[tid][0];
            st16_u2(dh, qhR[0]); st16_u2(dh + 8, qhR[1]);
            st16_u2(dh + 16, qhR2[0]); st16_u2(dh + 24, qhR2[1]);
            st16_u2(dl, qlR[0]); st16_u2(dl + 8, qlR[1]);
            st16_u2(dl + 16, qlR2[0]); st16_u2(dl + 24, qlR2[1]);
        }
        // store P hi/lo (split fp32 in regs)
        {
            uint h0 = pack2bf(pv0.x, pv0.y), h1 = pack2bf(pv0.z, pv0.w);
            uint h2 = pack2bf(pv1.x, pv1.y), h3 = pack2bf(pv1.z, pv1.w);
            uint l0 = pack2bf(pv0.x - __uint_as_float(h0 << 16),
                              pv0.y - __uint_as_float(h0 & 0xffff0000u));
            uint l1 = pack2bf(pv0.z - __uint_as_float(h1 << 16),
                              pv0.w - __uint_as_float(h1 & 0xffff0000u));
            uint l2 = pack2bf(pv1.x - __uint_as_float(h2 << 16),
                              pv1.y - __uint_as_float(h2 & 0xffff0000u));
            uint l3 = pack2bf(pv1.z - __uint_as_float(h3 << 16),
                              pv1.w - __uint_as_float(h3 & 0xffff0000u));
            st16_u2(&PhiL[prow_][pcg], make_uint4(h0, h1, h2, h3));
            st16_u2(&PloL[prow_][pcg], make_uint4(l0, l1, l2, l3));
        }
        __syncthreads();
        if (kc < 7) {
            int kn = k0 + 32;
            const uint4* sh = (const uint4*)(qh + (size_t)tid * 256 + kn);
            const uint4* sl_ = (const uint4*)(ql + (size_t)tid * 256 + kn);
            qhR[0] = sh[0]; qhR[1] = sh[1]; qhR2[0] = sh[2]; qhR2[1] = sh[3];
            qlR[0] = sl_[0]; qlR[1] = sl_[1]; qlR2[0] = sl_[2]; qlR2[1] = sl_[3];
            const float* pr = pbase + (size_t)(s0 + prow_) * NBD2 + kn + pcg;
            pv0 = *(const float4*)pr;
            pv1 = *(const float4*)(pr + 4);
        }
        {
            int kk = quad * 8;
            bf16x8 ah[4], al_[4], bh[4], bl_[4];
#pragma unroll
            for (int mi = 0; mi < 4; mi++) {
                ah[mi] = ld8(&PhiL[mi * 16 + colq][kk]);
                al_[mi] = ld8(&PloL[mi * 16 + colq][kk]);
            }
#pragma unroll
            for (int ni = 0; ni < 4; ni++) {
                bh[ni] = ld8(&QhiL[wave * 64 + ni * 16 + colq][kk]);
                bl_[ni] = ld8(&QloL[wave * 64 + ni * 16 + colq][kk]);
            }
#pragma unroll
            for (int mi = 0; mi < 4; mi++)
#pragma unroll
                for (int ni = 0; ni < 4; ni++) {
                    acc[mi][ni] = __builtin_amdgcn_mfma_f32_16x16x32_bf16(
                        ah[mi], bh[ni], acc[mi][ni], 0, 0, 0);
                    acc[mi][ni] = __builtin_amdgcn_mfma_f32_16x16x32_bf16(
                        ah[mi], bl_[ni], acc[mi][ni], 0, 0, 0);
                    acc[mi][ni] = __builtin_amdgcn_mfma_f32_16x16x32_bf16(
                        al_[mi], bh[ni], acc[mi][ni], 0, 0, 0);
                }
        }
    }

    // normalize, write alpha bf16 to ws, reduce sum/argmax
    float nqv[4];
#pragma unroll
    for (int ni = 0; ni < 4; ni++)
        nqv[ni] = normQ[normIdx(dir, 32, b, wave * 64 + ni * 16 + colq)];

#pragma unroll
    for (int mi = 0; mi < 4; mi++) {
        int rowbase = mi * 16 + quad * 4;
        float npa[4];
#pragma unroll
        for (int rg = 0; rg < 4; rg++)
            npa[rg] = normP[normIdx(dir, 32, b, s0 + rowbase + rg)];
        float av[4][4];
#pragma unroll
        for (int ni = 0; ni < 4; ni++)
#pragma unroll
            for (int rg = 0; rg < 4; rg++)
                av[ni][rg] = acc[mi][ni][rg] / fmaxf(npa[rg] * nqv[ni], EPSF);
#pragma unroll
        for (int ni = 0; ni < 4; ni++)
#pragma unroll
            for (int rg = 0; rg < 4; rg++)
                aW[(size_t)(s0 + rowbase + rg) * 256 + wave * 64 + ni * 16 + colq] =
                    (__bf16)av[ni][rg];
#pragma unroll
        for (int rg = 0; rg < 4; rg++) {
            float sm = av[0][rg] + av[1][rg] + av[2][rg] + av[3][rg];
            float mx = av[0][rg];
            int ix = wave * 64 + colq;
#pragma unroll
            for (int ni = 1; ni < 4; ni++) {
                if (av[ni][rg] > mx) { mx = av[ni][rg]; ix = wave * 64 + ni * 16 + colq; }
            }
#pragma unroll
            for (int off = 1; off < 16; off <<= 1) {
                sm += __shfl_xor(sm, off, 64);
                float m2 = __shfl_xor(mx, off, 64);
                int i2 = __shfl_xor(ix, off, 64);
                if (m2 > mx || (m2 == mx && i2 < ix)) { mx = m2; ix = i2; }
            }
            if (colq == 0) {
                redS[wave][rowbase + rg] = sm;
                redM[wave][rowbase + rg] = mx;
                redI[wave][rowbase + rg] = ix;
            }
        }
    }
    __syncthreads();
    if (tid < 64) {
        float sm = redS[0][tid] + redS[1][tid] + redS[2][tid] + redS[3][tid];
        float mx = redM[0][tid];
        int ix = redI[0][tid];
#pragma unroll
        for (int w = 1; w < 4; w++) {
            float m2 = redM[w][tid];
            int i2 = redI[w][tid];
            if (m2 > mx || (m2 == mx && i2 < ix)) { mx = m2; ix = i2; }
        }
        asumW[s0 + tid] = sm;
        aidxW[s0 + tid] = ix;
    }
}

// ---------------------------------------------------------------------------
// K_hout: h = alpha . q (bf16 MFMA), then E-GEMM epilogue. Conflict-free
// strides (68 / 260). grid 1024.
// ---------------------------------------------------------------------------
__global__ __launch_bounds__(256) void k_hout(const float* __restrict__ p,
                                              const float* __restrict__ W,
                                              char* __restrict__ wsb,
                                              float* __restrict__ out)
{
    int blk = blockIdx.x;
    int grp = blk & 255;
    int st = blk >> 8;
    int b = grp & 127, dir = grp >> 7;
    int s0 = st * 64;
    int tid = threadIdx.x;
    int wave = tid >> 6, lane = tid & 63;
    int colq = lane & 15, quad = lane >> 4;

    const float* normP = (const float*)wsb;
    const float* normQ = normP + NORM_ELEMS;
    size_t slice = (size_t)(dir * 128 + b) << 16;
    const __bf16* qh = (const __bf16*)(wsb + OFF_QHI) + slice;
    const __bf16* qt = (const __bf16*)(wsb + OFF_QT) + slice;
    const __bf16* aW = (const __bf16*)(wsb + OFF_ALPHA) + slice;
    const float* asumW = (const float*)(wsb + OFF_ASUM) + (size_t)(dir * 128 + b) * 256;
    const int* aidxW = (const int*)(wsb + OFF_AIDX) + (size_t)(dir * 128 + b) * 256;

    // union region: phase3 alphaA[64][68] + QTl[256][68] = 43520 B
    //               phase4 E[64][260] + W45[16][260] = 41600 B
    __shared__ __align__(16) char reg0[43520];
    __bf16* alphaA = (__bf16*)reg0;              // [64][68]
    __bf16* QTl = alphaA + 64 * 68;              // [256][68]
    __bf16* E = (__bf16*)reg0;                   // [64][260]
    __bf16* W45 = E + 64 * 260;                  // [16][260]
    __shared__ int   aidxL[64];
    __shared__ float asumL[64];

    if (tid < 64) { aidxL[tid] = aidxW[s0 + tid]; asumL[tid] = asumW[s0 + tid]; }

    const float* pbase = p + (size_t)b * D2 + dir * HALF;

    f32x4 acc[4][4];
#pragma unroll
    for (int mi = 0; mi < 4; mi++)
#pragma unroll
        for (int ni = 0; ni < 4; ni++)
#pragma unroll
            for (int k = 0; k < 4; k++) acc[mi][ni][k] = 0.f;

    // phase 3: h[s][d] = sum_t alpha[s][t] q[t][d]; K = t, 4 chunks of 64
    int arow = tid >> 2, acp = (tid & 3) * 16;
    uint4 aR[2], qR[8];
    {
        const uint4* src = (const uint4*)(aW + (size_t)(s0 + arow) * 256 + acp);
        aR[0] = src[0]; aR[1] = src[1];
        const uint4* sq = (const uint4*)(qt + (size_t)tid * 256);
#pragma unroll
        for (int j = 0; j < 8; j++) qR[j] = sq[j];
    }
    for (int tc = 0; tc < 4; tc++) {
        __syncthreads();
        {
            __bf16* dst = &alphaA[arow * 68 + acp];
            st16_u2(dst, aR[0]); st16_u2(dst + 8, aR[1]);
            __bf16* dq = &QTl[tid * 68];
#pragma unroll
            for (int j = 0; j < 8; j++) st16_u2(dq + j * 8, qR[j]);
        }
        __syncthreads();
        if (tc < 3) {
            const uint4* src = (const uint4*)(aW + (size_t)(s0 + arow) * 256 + (tc + 1) * 64 + acp);
            aR[0] = src[0]; aR[1] = src[1];
            const uint4* sq = (const uint4*)(qt + (size_t)tid * 256 + (tc + 1) * 64);
#pragma unroll
            for (int j = 0; j < 8; j++) qR[j] = sq[j];
        }
#pragma unroll
        for (int step = 0; step < 2; step++) {
            int kk = step * 32 + quad * 8;
            bf16x8 af[4], bfr[4];
#pragma unroll
            for (int mi = 0; mi < 4; mi++)
                af[mi] = ld8(&alphaA[(mi * 16 + colq) * 68 + kk]);
#pragma unroll
            for (int ni = 0; ni < 4; ni++)
                bfr[ni] = ld8(&QTl[(wave * 64 + ni * 16 + colq) * 68 + kk]);
#pragma unroll
            for (int mi = 0; mi < 4; mi++)
#pragma unroll
                for (int ni = 0; ni < 4; ni++)
                    acc[mi][ni] = __builtin_amdgcn_mfma_f32_16x16x32_bf16(
                        af[mi], bfr[ni], acc[mi][ni], 0, 0, 0);
        }
    }

    // epilogue: E-GEMMs vs [W4^2; W5^2]
    __syncthreads();
    {
        int n = tid >> 4, dblk = (tid & 15) * 16;
        int wrow = (n < 8) ? (4 * 8 + n) : (5 * 8 + (n - 8));
        const float* wr = W + (size_t)wrow * HALF + dblk;
        float4 a = *(const float4*)wr;
        float4 bq = *(const float4*)(wr + 4);
        float4 c = *(const float4*)(wr + 8);
        float4 d4 = *(const float4*)(wr + 12);
        uint u0 = pack2bf(a.x * a.x, a.y * a.y), u1 = pack2bf(a.z * a.z, a.w * a.w);
        uint u2 = pack2bf(bq.x * bq.x, bq.y * bq.y), u3 = pack2bf(bq.z * bq.z, bq.w * bq.w);
        uint u4 = pack2bf(c.x * c.x, c.y * c.y), u5 = pack2bf(c.z * c.z, c.w * c.w);
        uint u6 = pack2bf(d4.x * d4.x, d4.y * d4.y), u7 = pack2bf(d4.z * d4.z, d4.w * d4.w);
        __bf16* dst = &W45[n * 260 + dblk];
        st16_u2(dst, make_uint4(u0, u1, u2, u3));
        st16_u2(dst + 8, make_uint4(u4, u5, u6, u7));
    }

    f32x4 c1, c2, c3;
#pragma unroll
    for (int k = 0; k < 4; k++) { c1[k] = 0.f; c2[k] = 0.f; c3[k] = 0.f; }

    // E1 = p .* h
#pragma unroll
    for (int mi = 0; mi < 4; mi++)
#pragma unroll
        for (int rg = 0; rg < 4; rg++) {
            int sl = mi * 16 + quad * 4 + rg;
            const float* prow = pbase + (size_t)(s0 + sl) * NBD2;
#pragma unroll
            for (int ni = 0; ni < 4; ni++) {
                int d = wave * 64 + ni * 16 + colq;
                E[sl * 260 + d] = (__bf16)(prow[d] * acc[mi][ni][rg]);
            }
        }
    __syncthreads();
#pragma unroll
    for (int step = 0; step < 8; step++) {
        int kk = step * 32 + quad * 8;
        bf16x8 ea = ld8(&E[(wave * 16 + colq) * 260 + kk]);
        bf16x8 wb = ld8(&W45[colq * 260 + kk]);
        c1 = __builtin_amdgcn_mfma_f32_16x16x32_bf16(ea, wb, c1, 0, 0, 0);
    }
    __syncthreads();

    // E2 = h .* h
#pragma unroll
    for (int mi = 0; mi < 4; mi++)
#pragma unroll
        for (int rg = 0; rg < 4; rg++) {
            int sl = mi * 16 + quad * 4 + rg;
#pragma unroll
            for (int ni = 0; ni < 4; ni++) {
                int d = wave * 64 + ni * 16 + colq;
                float hv = acc[mi][ni][rg];
                E[sl * 260 + d] = (__bf16)(hv * hv);
            }
        }
    __syncthreads();
#pragma unroll
    for (int step = 0; step < 8; step++) {
        int kk = step * 32 + quad * 8;
        bf16x8 ea = ld8(&E[(wave * 16 + colq) * 260 + kk]);
        bf16x8 wb = ld8(&W45[colq * 260 + kk]);
        c2 = __builtin_amdgcn_mfma_f32_16x16x32_bf16(ea, wb, c2, 0, 0, 0);
    }
    __syncthreads();

    // E3 = p .* q[aidx]
#pragma unroll
    for (int mi = 0; mi < 4; mi++)
#pragma unroll
        for (int rg = 0; rg < 4; rg++) {
            int sl = mi * 16 + quad * 4 + rg;
            const float* prow = pbase + (size_t)(s0 + sl) * NBD2;
            const __bf16* qrow = qh + (size_t)aidxL[sl] * 256;
#pragma unroll
            for (int ni = 0; ni < 4; ni++) {
                int d = wave * 64 + ni * 16 + colq;
                E[sl * 260 + d] = (__bf16)(prow[d] * (float)qrow[d]);
            }
        }
    __syncthreads();
#pragma unroll
    for (int step = 0; step < 8; step++) {
        int kk = step * 32 + quad * 8;
        bf16x8 ea = ld8(&E[(wave * 16 + colq) * 260 + kk]);
        bf16x8 wb = ld8(&W45[colq * 260 + kk]);
        c3 = __builtin_amdgcn_mfma_f32_16x16x32_bf16(ea, wb, c3, 0, 0, 0);
    }

    // write out: rows s = wave*16 + quad*4 + rg, col n = colq
#pragma unroll
    for (int rg = 0; rg < 4; rg++) {
        int sl = wave * 16 + quad * 4 + rg;
        size_t ob = ((size_t)(s0 + sl) * NB + b) * 64;
        if (colq < 8) {
            int l = colq;
            float np4 = normP[normIdx(dir, 16 + l, b, s0 + sl)];
            float nh = sqrtf(fmaxf(c2[rg], 0.f));
            float sgn = (asumL[sl] < 0.f) ? -1.f : 1.f;
            out[ob + 32 + dir * 8 + l] = sgn * c1[rg] / fmaxf(np4 * nh, EPSF);
        } else {
            int l = colq - 8;
            float np5 = normP[normIdx(dir, 24 + l, b, s0 + sl)];
            float nq5 = normQ[normIdx(dir, 24 + l, b, aidxL[sl])];
            out[ob + 48 + dir * 8 + l] = c3[rg] / fmaxf(np5 * nq5, EPSF);
        }
    }
}

// ---------------------------------------------------------------------------
extern "C" void kernel_launch(void* const* d_in, const int* in_sizes, int n_in,
                              void* d_out, int out_size, void* d_ws, size_t ws_size,
                              hipStream_t stream)
{
    (void)in_sizes; (void)n_in; (void)out_size;
    if (ws_size < WS_NEED) return;
    const float* p = (const float*)d_in[0];
    const float* q = (const float*)d_in[1];
    const float* W = (const float*)d_in[2];
    float* out = (float*)d_out;
    float* ws = (float*)d_ws;
    char* wsb = (char*)d_ws;

    hipLaunchKernelGGL(k_norms, dim3(512), dim3(256), 0, stream, p, q, W, ws);
    hipLaunchKernelGGL(k_packA, dim3(1024), dim3(256), 0, stream, q, wsb);
    hipLaunchKernelGGL(k_packT, dim3(256), dim3(256), 0, stream, wsb);
    hipLaunchKernelGGL(k_full, dim3(2048), dim3(256), 0, stream, p, q, W, ws, out);
    hipLaunchKernelGGL(k_maxpool4, dim3(4096), dim3(256), 0, stream, p, W, wsb, out);
    hipLaunchKernelGGL(k_alpha, dim3(1024), dim3(256), 0, stream, p, wsb);
    hipLaunchKernelGGL(k_hout, dim3(1024), dim3(256), 0, stream, p, W, wsb, out);
}